// Round 6
// baseline (390.342 us; speedup 1.0000x reference)
//
#include <hip/hip_runtime.h>

// Problem constants
#define B_  4
#define S_  2048
#define D_  1024
#define H_  16
#define HD_ 64
#define M_  (B_*S_)   // 8192 rows total

typedef _Float16 f16;
typedef f16  f16x8 __attribute__((ext_vector_type(8)));
typedef f16  f16x4 __attribute__((ext_vector_type(4)));
typedef float f32x4 __attribute__((ext_vector_type(4)));

// global -> LDS direct DMA, 16B per lane. LDS dest = wave-uniform base + lane*16.
__device__ __forceinline__ void gload_lds16(const f16* g, f16* l) {
    __builtin_amdgcn_global_load_lds(
        (const __attribute__((address_space(1))) void*)g,
        (__attribute__((address_space(3))) void*)l, 16, 0, 0);
}

// ---------------------------------------------------------------- converts
__global__ __launch_bounds__(256) void cvt_kernel(const float* __restrict__ in,
                                                  f16* __restrict__ out, int n4) {
    int i = blockIdx.x * 256 + threadIdx.x;
    if (i < n4) {
        f32x4 v = *reinterpret_cast<const f32x4*>(in + (size_t)i * 4);
        *reinterpret_cast<f16x4*>(out + (size_t)i * 4) = __builtin_convertvector(v, f16x4);
    }
}

// W[K=1024][N=1024] f32 -> WT[N][K] f16
__global__ __launch_bounds__(256) void transpose_cvt_kernel(const float* __restrict__ W,
                                                            f16* __restrict__ WT) {
    __shared__ float tile[32][33];
    const int n0 = blockIdx.x * 32, k0 = blockIdx.y * 32;
    const int tx = threadIdx.x, ty = threadIdx.y; // (32,8)
#pragma unroll
    for (int j = 0; j < 4; ++j)
        tile[ty + 8 * j][tx] = W[(size_t)(k0 + ty + 8 * j) * D_ + n0 + tx];
    __syncthreads();
#pragma unroll
    for (int j = 0; j < 4; ++j)
        WT[(size_t)(n0 + ty + 8 * j) * D_ + k0 + tx] = (f16)tile[tx][ty + 8 * j];
}

// ---------------------------------------------------------------- GEMM  C = A @ Bt^T + bias
// MODE 0: OutT=f16 row-major [M][D].  MODE 1: float row-major (final output).
// MODE 2: f16, output written transposed per-head: VT[B][H][HD][S] (for attention V).
// Double-buffered LDS staging via global_load_lds: stage(t+1) overlaps MFMA(t).
template <int MODE, typename OutT>
__global__ __launch_bounds__(256) void gemm_bt(const f16* __restrict__ A,
                                               const f16* __restrict__ Bt,
                                               const float* __restrict__ bias,
                                               OutT* __restrict__ C) {
    constexpr int K = D_;
    constexpr int NT = K / 32; // 32 K-steps
    __shared__ __align__(16) f16 Al[2][128 * 32]; // linear [row][32] per buffer
    __shared__ __align__(16) f16 Bl[2][128 * 32];
    const int m0 = blockIdx.y * 128, n0 = blockIdx.x * 128;
    const int tid = threadIdx.x;
    const int w = tid >> 6, l = tid & 63, lr = l & 15, lg = l >> 4;
    const int wr = w >> 1, wc = w & 1;
    const int srow = tid >> 2, soff = (tid & 3) * 8; // this thread's staging chunk

    auto stage = [&](int buf, int kk) {
#pragma unroll
        for (int i = 0; i < 2; ++i) { // chunks c = tid, tid+256
            const int row = srow + i * 64;
            gload_lds16(A  + (size_t)(m0 + row) * K + kk + soff, &Al[buf][(w + 4 * i) * 512]);
            gload_lds16(Bt + (size_t)(n0 + row) * K + kk + soff, &Bl[buf][(w + 4 * i) * 512]);
        }
    };

    f32x4 acc[4][4] = {};
    stage(0, 0);
    __syncthreads(); // drains vmcnt -> buf0 ready
    for (int t = 0; t < NT; ++t) {
        const int buf = t & 1;
        if (t + 1 < NT) stage(buf ^ 1, (t + 1) * 32); // in flight during MFMA below
        f16x8 a[4], b[4];
#pragma unroll
        for (int m = 0; m < 4; ++m)
            a[m] = *reinterpret_cast<const f16x8*>(&Al[buf][(wr * 64 + m * 16 + lr) * 32 + lg * 8]);
#pragma unroll
        for (int n = 0; n < 4; ++n)
            b[n] = *reinterpret_cast<const f16x8*>(&Bl[buf][(wc * 64 + n * 16 + lr) * 32 + lg * 8]);
        __builtin_amdgcn_s_setprio(1);
#pragma unroll
        for (int m = 0; m < 4; ++m)
#pragma unroll
            for (int n = 0; n < 4; ++n)
                acc[m][n] = __builtin_amdgcn_mfma_f32_16x16x32_f16(a[m], b[n], acc[m][n], 0, 0, 0);
        __builtin_amdgcn_s_setprio(0);
        __syncthreads(); // drains vmcnt -> next buf ready, and protects buf reuse
    }
#pragma unroll
    for (int n = 0; n < 4; ++n) {
        const int col = n0 + wc * 64 + n * 16 + lr;
        const float bv = bias[col];
#pragma unroll
        for (int m = 0; m < 4; ++m) {
            const int row = m0 + wr * 64 + m * 16 + lg * 4;
            if (MODE == 2) {
                const int bb = row >> 11, s0 = row & 2047;
                f16x4 v;
#pragma unroll
                for (int r = 0; r < 4; ++r) v[r] = (f16)(acc[m][n][r] + bv);
                *reinterpret_cast<f16x4*>((f16*)C + ((size_t)(bb * D_ + col)) * S_ + s0) = v;
            } else {
#pragma unroll
                for (int r = 0; r < 4; ++r)
                    C[(size_t)(row + r) * D_ + col] = (OutT)(acc[m][n][r] + bv);
            }
        }
    }
}

// ---------------------------------------------------------------- causal flash attention
// grid (H, B, 64), 64 threads = ONE wave per block. Block z handles q-chunks
// {127-z, z} (16 rows each): nt(c)=c/4+1 -> every block does exactly 33 tiles.
// 4096 identical-work waves, 16 blocks/CU = 4 waves/SIMD -> TLP hides latency.
// Swapped QK^T (lane owns q-row lr's scores in-register), defer-max, P via LDS.
__global__ __launch_bounds__(64, 4) void attn_kernel(const f16* __restrict__ Q,
                                                     const f16* __restrict__ Kg,
                                                     const f16* __restrict__ Vt,
                                                     f16* __restrict__ Z) {
    __shared__ __align__(16) f16 Pl[16][72]; // P (16q x 64k), padded
    const int h = blockIdx.x, b = blockIdx.y, z = blockIdx.z; // z in 0..63
    const int l = threadIdx.x, lr = l & 15, lg = l >> 4;
    const size_t base   = ((size_t)b * S_) * D_ + h * HD_;
    const size_t vtbase = ((size_t)(b * D_ + h * HD_)) * S_;
    const f16* __restrict__ Kbase = Kg + base;
    const f16* __restrict__ Vbase = Vt + vtbase;
    const float sc = 0.125f * 1.44269504f; // 1/sqrt(64) * log2(e)

    for (int half = 0; half < 2; ++half) {
        const int c = half ? z : (127 - z); // heavy chunk first
        const int wq0 = c * 16;
        const int nt = (c >> 2) + 1;

        f16x8 qf[2];
#pragma unroll
        for (int kd = 0; kd < 2; ++kd)
            qf[kd] = *reinterpret_cast<const f16x8*>(
                Q + base + (size_t)(wq0 + lr) * D_ + kd * 32 + lg * 8);

        f32x4 zacc[4] = {};
        float mrun = -3.0e38f, lsum = 0.f;

        for (int t = 0; t < nt; ++t) {
            const int t0 = t * 64;
            // ---- K frags (A-operand): row = key, k = kd*32+lg*8
            f16x8 kf[2][4];
#pragma unroll
            for (int kd = 0; kd < 2; ++kd)
#pragma unroll
                for (int n = 0; n < 4; ++n)
                    kf[kd][n] = *reinterpret_cast<const f16x8*>(
                        Kbase + (size_t)(t0 + n * 16 + lr) * D_ + kd * 32 + lg * 8);
            // ---- S^T = K Q^T : lane owns q = lr; keys at n*16 + lg*4 + r
            f32x4 sf[4] = {};
            __builtin_amdgcn_s_setprio(1);
#pragma unroll
            for (int kd = 0; kd < 2; ++kd)
#pragma unroll
                for (int n = 0; n < 4; ++n)
                    sf[n] = __builtin_amdgcn_mfma_f32_16x16x32_f16(kf[kd][n], qf[kd], sf[n], 0, 0, 0);
            __builtin_amdgcn_s_setprio(0);
            // ---- V frags issued now; consumed at PV (L2 latency hides under softmax)
            f16x8 vf[2][4];
#pragma unroll
            for (int kt = 0; kt < 2; ++kt)
#pragma unroll
                for (int n = 0; n < 4; ++n)
                    vf[kt][n] = *reinterpret_cast<const f16x8*>(
                        Vbase + (size_t)(n * 16 + lr) * S_ + t0 + kt * 32 + lg * 8);
            // ---- scale (+ mask on the final tile)
            if (t == nt - 1) {
#pragma unroll
                for (int n = 0; n < 4; ++n)
#pragma unroll
                    for (int r = 0; r < 4; ++r) {
                        const bool masked = (t0 + n * 16 + lg * 4 + r) > (wq0 + lr);
                        sf[n][r] = masked ? -3.0e38f : sf[n][r] * sc;
                    }
            } else {
#pragma unroll
                for (int n = 0; n < 4; ++n)
#pragma unroll
                    for (int r = 0; r < 4; ++r) sf[n][r] *= sc;
            }
            // ---- online softmax with defer-max; lane owns q = lr
            f32x4 t4;
#pragma unroll
            for (int r = 0; r < 4; ++r)
                t4[r] = fmaxf(fmaxf(sf[0][r], sf[1][r]), fmaxf(sf[2][r], sf[3][r]));
            float vmax = fmaxf(fmaxf(t4[0], t4[1]), fmaxf(t4[2], t4[3]));
            vmax = fmaxf(vmax, __shfl_xor(vmax, 16));
            vmax = fmaxf(vmax, __shfl_xor(vmax, 32));
            const bool norm = !__all(vmax <= mrun + 10.0f); // wave-uniform
            float al = 1.0f;
            if (norm) {
                const float mnew = fmaxf(mrun, vmax);
                al = __builtin_amdgcn_exp2f(mrun - mnew);
                mrun = mnew;
            }
            float s = 0.f;
#pragma unroll
            for (int n = 0; n < 4; ++n) {
                f32x4 p;
#pragma unroll
                for (int r = 0; r < 4; ++r) p[r] = __builtin_amdgcn_exp2f(sf[n][r] - mrun);
                sf[n] = p;
                s += (p[0] + p[1]) + (p[2] + p[3]);
            }
            s += __shfl_xor(s, 16);
            s += __shfl_xor(s, 32);
            // ---- P -> LDS (wave-internal, no barrier)
#pragma unroll
            for (int n = 0; n < 4; ++n) {
                f16x4 pv;
#pragma unroll
                for (int r = 0; r < 4; ++r) pv[r] = (f16)sf[n][r];
                *reinterpret_cast<f16x4*>(&Pl[lr][n * 16 + lg * 4]) = pv;
            }
            if (norm) {
                lsum = lsum * al + s;
#pragma unroll
                for (int r = 0; r < 4; ++r) {
                    const float ar = __shfl(al, lg * 4 + r);
#pragma unroll
                    for (int n = 0; n < 4; ++n) zacc[n][r] *= ar;
                }
            } else {
                lsum += s;
            }
            // ---- Z += P V
            f16x8 pa[2];
#pragma unroll
            for (int kt = 0; kt < 2; ++kt)
                pa[kt] = *reinterpret_cast<const f16x8*>(&Pl[lr][kt * 32 + lg * 8]);
            __builtin_amdgcn_s_setprio(1);
#pragma unroll
            for (int kt = 0; kt < 2; ++kt)
#pragma unroll
                for (int n = 0; n < 4; ++n)
                    zacc[n] = __builtin_amdgcn_mfma_f32_16x16x32_f16(pa[kt], vf[kt][n], zacc[n], 0, 0, 0);
            __builtin_amdgcn_s_setprio(0);
        }
        // ---- epilogue: divide by lsum (broadcast per row) and store
        const float inv = 1.0f / lsum;
#pragma unroll
        for (int r = 0; r < 4; ++r) {
            const float ir = __shfl(inv, lg * 4 + r);
#pragma unroll
            for (int n = 0; n < 4; ++n)
                Z[base + (size_t)(wq0 + lg * 4 + r) * D_ + n * 16 + lr] =
                    (f16)(zacc[n][r] * ir);
        }
    }
}

// ---------------------------------------------------------------- launcher
extern "C" void kernel_launch(void* const* d_in, const int* in_sizes, int n_in,
                              void* d_out, int out_size, void* d_ws, size_t ws_size,
                              hipStream_t stream) {
    const float* data    = (const float*)d_in[0];
    const float* context = (const float*)d_in[1];
    const float* Wq = (const float*)d_in[2];
    const float* bq = (const float*)d_in[3];
    const float* Wk = (const float*)d_in[4];
    const float* bk = (const float*)d_in[5];
    const float* Wv = (const float*)d_in[6];
    const float* bv = (const float*)d_in[7];
    const float* Wo = (const float*)d_in[8];
    const float* bo = (const float*)d_in[9];

    const size_t MD = (size_t)M_ * D_;
    const size_t DD = (size_t)D_ * D_;
    f16* dataB = (f16*)d_ws;
    f16* ctxB  = dataB + MD;
    f16* WqT   = ctxB + MD;
    f16* WkT   = WqT + DD;
    f16* WvT   = WkT + DD;
    f16* WoT   = WvT + DD;
    f16* Qb    = WoT + DD;
    f16* Kb    = Qb + MD;
    f16* VtB   = Kb + MD;  // [B][H][HD][S]
    f16* Zb    = VtB + MD;

    const int n4 = (int)(MD / 4);
    cvt_kernel<<<n4 / 256, 256, 0, stream>>>(data, dataB, n4);
    cvt_kernel<<<n4 / 256, 256, 0, stream>>>(context, ctxB, n4);
    dim3 tb(32, 8), tg(32, 32);
    transpose_cvt_kernel<<<tg, tb, 0, stream>>>(Wq, WqT);
    transpose_cvt_kernel<<<tg, tb, 0, stream>>>(Wk, WkT);
    transpose_cvt_kernel<<<tg, tb, 0, stream>>>(Wv, WvT);
    transpose_cvt_kernel<<<tg, tb, 0, stream>>>(Wo, WoT);

    dim3 gg(D_ / 128, M_ / 128); // (8, 64)
    gemm_bt<0, f16><<<gg, 256, 0, stream>>>(dataB, WqT, bq, Qb);
    gemm_bt<0, f16><<<gg, 256, 0, stream>>>(ctxB,  WkT, bk, Kb);
    gemm_bt<2, f16><<<gg, 256, 0, stream>>>(ctxB,  WvT, bv, VtB);

    attn_kernel<<<dim3(H_, B_, 64), 64, 0, stream>>>(Qb, Kb, VtB, Zb);

    gemm_bt<1, float><<<gg, 256, 0, stream>>>(Zb, WoT, bo, (float*)d_out);
}

// Round 7
// 228.902 us; speedup vs baseline: 1.7053x; 1.7053x over previous
//
#include <hip/hip_runtime.h>

// Problem constants
#define B_  4
#define S_  2048
#define D_  1024
#define H_  16
#define HD_ 64
#define M_  (B_*S_)   // 8192 rows total

typedef _Float16 f16;
typedef f16  f16x8 __attribute__((ext_vector_type(8)));
typedef f16  f16x4 __attribute__((ext_vector_type(4)));
typedef float f32x4 __attribute__((ext_vector_type(4)));

// global -> LDS direct DMA, 16B per lane. LDS dest = wave-uniform base + lane*16.
__device__ __forceinline__ void gload_lds16(const f16* g, f16* l) {
    __builtin_amdgcn_global_load_lds(
        (const __attribute__((address_space(1))) void*)g,
        (__attribute__((address_space(3))) void*)l, 16, 0, 0);
}

// ---------------------------------------------------------------- converts
__global__ __launch_bounds__(256) void cvt_kernel(const float* __restrict__ in,
                                                  f16* __restrict__ out, int n4) {
    int i = blockIdx.x * 256 + threadIdx.x;
    if (i < n4) {
        f32x4 v = *reinterpret_cast<const f32x4*>(in + (size_t)i * 4);
        *reinterpret_cast<f16x4*>(out + (size_t)i * 4) = __builtin_convertvector(v, f16x4);
    }
}

// W[K=1024][N=1024] f32 -> WT[N][K] f16
__global__ __launch_bounds__(256) void transpose_cvt_kernel(const float* __restrict__ W,
                                                            f16* __restrict__ WT) {
    __shared__ float tile[32][33];
    const int n0 = blockIdx.x * 32, k0 = blockIdx.y * 32;
    const int tx = threadIdx.x, ty = threadIdx.y; // (32,8)
#pragma unroll
    for (int j = 0; j < 4; ++j)
        tile[ty + 8 * j][tx] = W[(size_t)(k0 + ty + 8 * j) * D_ + n0 + tx];
    __syncthreads();
#pragma unroll
    for (int j = 0; j < 4; ++j)
        WT[(size_t)(n0 + ty + 8 * j) * D_ + k0 + tx] = (f16)tile[tx][ty + 8 * j];
}

// ---------------------------------------------------------------- GEMM  C = A @ Bt^T + bias
// MODE 0: OutT=f16 row-major [M][D].  MODE 1: float row-major (final output).
// MODE 2: f16, output written transposed per-head: VT[B][H][HD][S] (for attention V).
// Double-buffered LDS staging via global_load_lds: stage(t+1) overlaps MFMA(t).
template <int MODE, typename OutT>
__global__ __launch_bounds__(256) void gemm_bt(const f16* __restrict__ A,
                                               const f16* __restrict__ Bt,
                                               const float* __restrict__ bias,
                                               OutT* __restrict__ C) {
    constexpr int K = D_;
    constexpr int NT = K / 32; // 32 K-steps
    __shared__ __align__(16) f16 Al[2][128 * 32]; // linear [row][32] per buffer
    __shared__ __align__(16) f16 Bl[2][128 * 32];
    const int m0 = blockIdx.y * 128, n0 = blockIdx.x * 128;
    const int tid = threadIdx.x;
    const int w = tid >> 6, l = tid & 63, lr = l & 15, lg = l >> 4;
    const int wr = w >> 1, wc = w & 1;
    const int srow = tid >> 2, soff = (tid & 3) * 8; // this thread's staging chunk

    auto stage = [&](int buf, int kk) {
#pragma unroll
        for (int i = 0; i < 2; ++i) { // chunks c = tid, tid+256
            const int row = srow + i * 64;
            gload_lds16(A  + (size_t)(m0 + row) * K + kk + soff, &Al[buf][(w + 4 * i) * 512]);
            gload_lds16(Bt + (size_t)(n0 + row) * K + kk + soff, &Bl[buf][(w + 4 * i) * 512]);
        }
    };

    f32x4 acc[4][4] = {};
    stage(0, 0);
    __syncthreads(); // drains vmcnt -> buf0 ready
    for (int t = 0; t < NT; ++t) {
        const int buf = t & 1;
        if (t + 1 < NT) stage(buf ^ 1, (t + 1) * 32); // in flight during MFMA below
        f16x8 a[4], b[4];
#pragma unroll
        for (int m = 0; m < 4; ++m)
            a[m] = *reinterpret_cast<const f16x8*>(&Al[buf][(wr * 64 + m * 16 + lr) * 32 + lg * 8]);
#pragma unroll
        for (int n = 0; n < 4; ++n)
            b[n] = *reinterpret_cast<const f16x8*>(&Bl[buf][(wc * 64 + n * 16 + lr) * 32 + lg * 8]);
        __builtin_amdgcn_s_setprio(1);
#pragma unroll
        for (int m = 0; m < 4; ++m)
#pragma unroll
            for (int n = 0; n < 4; ++n)
                acc[m][n] = __builtin_amdgcn_mfma_f32_16x16x32_f16(a[m], b[n], acc[m][n], 0, 0, 0);
        __builtin_amdgcn_s_setprio(0);
        __syncthreads(); // drains vmcnt -> next buf ready, and protects buf reuse
    }
#pragma unroll
    for (int n = 0; n < 4; ++n) {
        const int col = n0 + wc * 64 + n * 16 + lr;
        const float bv = bias[col];
#pragma unroll
        for (int m = 0; m < 4; ++m) {
            const int row = m0 + wr * 64 + m * 16 + lg * 4;
            if (MODE == 2) {
                const int bb = row >> 11, s0 = row & 2047;
                f16x4 v;
#pragma unroll
                for (int r = 0; r < 4; ++r) v[r] = (f16)(acc[m][n][r] + bv);
                *reinterpret_cast<f16x4*>((f16*)C + ((size_t)(bb * D_ + col)) * S_ + s0) = v;
            } else {
#pragma unroll
                for (int r = 0; r < 4; ++r)
                    C[(size_t)(row + r) * D_ + col] = (OutT)(acc[m][n][r] + bv);
            }
        }
    }
}

// ---------------------------------------------------------------- causal flash attention
// grid (H, B, 8), 256 threads = 4 waves. Block handles q-tiles {15-pp, pp} (128 rows
// each): per-block work constant (36 KV-tiles), 512 blocks = 2/CU, all resident.
// K,V staged to LDS via global_load_lds (no VGPR round-trip -> loads pipeline),
// double-buffered, XOR-swizzled both sides (pre-swizzled DMA source + swizzled
// ds_read). Swapped QK^T (lane owns q-row's scores), defer-max, P via per-wave LDS.
__global__ __launch_bounds__(256, 2) void attn_kernel(const f16* __restrict__ Q,
                                                      const f16* __restrict__ Kg,
                                                      const f16* __restrict__ Vt,
                                                      f16* __restrict__ Z) {
    __shared__ __align__(16) f16 KL[2][64 * 64]; // [key][64 f16] rows, swizzled
    __shared__ __align__(16) f16 VL[2][64 * 64]; // [d][64 t f16] rows, swizzled
    __shared__ __align__(16) f16 Pl[4][32][72];  // per-wave P (32q x 64k), padded
    const int h = blockIdx.x, b = blockIdx.y, pp = blockIdx.z; // pp in 0..7
    const int tid = threadIdx.x, w = tid >> 6, l = tid & 63, lr = l & 15, lg = l >> 4;
    const size_t base   = ((size_t)b * S_) * D_ + h * HD_;
    const size_t vtbase = ((size_t)(b * D_ + h * HD_)) * S_;
    const f16* __restrict__ Kbase = Kg + base;
    const f16* __restrict__ Vbase = Vt + vtbase;
    const float sc = 0.125f * 1.44269504f; // 1/sqrt(64) * log2(e)
    // staging geometry: linear chunk c = i*256 + tid covers row c>>3, 16B-slot c&7;
    // source slot pre-swizzled so LDS holds (row, pos) = global (row, pos^(row&7)).
    const int sw_xor = lr & 7; // ds_read xor term (row & 7 == lr & 7 for row = n*16+lr)

    auto stageKV = [&](int buf, int t0) {
#pragma unroll
        for (int i = 0; i < 2; ++i) {
            const int c = i * 256 + tid;
            const int row = c >> 3, g16 = (c & 7) ^ (row & 7);
            f16* dstK = &KL[buf][(i * 256 + w * 64) * 8];
            f16* dstV = &VL[buf][(i * 256 + w * 64) * 8];
            gload_lds16(Kbase + (size_t)(t0 + row) * D_ + g16 * 8, dstK);
            gload_lds16(Vbase + (size_t)row * S_ + t0 + g16 * 8, dstV);
        }
    };

    for (int half = 0; half < 2; ++half) {
        const int qt = half ? pp : (15 - pp); // heavy tile first
        const int q0 = qt * 128, wq0 = q0 + w * 32;
        const int ntw = ((wq0 + 31) >> 6) + 1; // this wave's compute tiles
        const int ntb = qt * 2 + 2;            // block-uniform loop count

        f16x8 qf[2][2];
#pragma unroll
        for (int mf = 0; mf < 2; ++mf)
#pragma unroll
            for (int kd = 0; kd < 2; ++kd)
                qf[mf][kd] = *reinterpret_cast<const f16x8*>(
                    Q + base + (size_t)(wq0 + mf * 16 + lr) * D_ + kd * 32 + lg * 8);

        f32x4 zacc[2][4] = {};
        float mrun[2] = {-3.0e38f, -3.0e38f}, lsum[2] = {0.f, 0.f};

        stageKV(0, 0);
        __syncthreads(); // buf0 ready (vmcnt drained by barrier semantics)

        for (int t = 0; t < ntb; ++t) {
            const int buf = t & 1;
            if (t + 1 < ntb) stageKV(buf ^ 1, (t + 1) * 64); // async, lands during compute
            if (t < ntw) {
                const int t0 = t * 64;
                // ---- K frags from LDS (swizzled): row = key = n*16+lr
                f16x8 kf[2][4];
#pragma unroll
                for (int kd = 0; kd < 2; ++kd)
#pragma unroll
                    for (int n = 0; n < 4; ++n)
                        kf[kd][n] = *reinterpret_cast<const f16x8*>(
                            &KL[buf][(n * 16 + lr) * 64 + (((kd * 4 + lg) ^ sw_xor) * 8)]);
                // ---- S^T = K Q^T : lane owns q = lr; keys at n*16 + lg*4 + r
                f32x4 sf[2][4] = {};
                __builtin_amdgcn_s_setprio(1);
#pragma unroll
                for (int kd = 0; kd < 2; ++kd)
#pragma unroll
                    for (int n = 0; n < 4; ++n)
#pragma unroll
                        for (int mf = 0; mf < 2; ++mf)
                            sf[mf][n] = __builtin_amdgcn_mfma_f32_16x16x32_f16(kf[kd][n], qf[mf][kd], sf[mf][n], 0, 0, 0);
                __builtin_amdgcn_s_setprio(0);
                // ---- V frags from LDS, issued now (latency hides under softmax)
                f16x8 vf[2][4];
#pragma unroll
                for (int kt = 0; kt < 2; ++kt)
#pragma unroll
                    for (int n = 0; n < 4; ++n)
                        vf[kt][n] = *reinterpret_cast<const f16x8*>(
                            &VL[buf][(n * 16 + lr) * 64 + (((kt * 4 + lg) ^ sw_xor) * 8)]);
                // ---- scale (+ mask on this wave's diagonal tile)
                if (t == ntw - 1) {
#pragma unroll
                    for (int mf = 0; mf < 2; ++mf)
#pragma unroll
                        for (int n = 0; n < 4; ++n)
#pragma unroll
                            for (int r = 0; r < 4; ++r) {
                                const bool masked = (t0 + n * 16 + lg * 4 + r) > (wq0 + mf * 16 + lr);
                                sf[mf][n][r] = masked ? -3.0e38f : sf[mf][n][r] * sc;
                            }
                } else {
#pragma unroll
                    for (int mf = 0; mf < 2; ++mf)
#pragma unroll
                        for (int n = 0; n < 4; ++n)
#pragma unroll
                            for (int r = 0; r < 4; ++r) sf[mf][n][r] *= sc;
                }
                // ---- online softmax with defer-max; lane owns q = lr (per mf)
#pragma unroll
                for (int mf = 0; mf < 2; ++mf) {
                    f32x4 t4;
#pragma unroll
                    for (int r = 0; r < 4; ++r)
                        t4[r] = fmaxf(fmaxf(sf[mf][0][r], sf[mf][1][r]), fmaxf(sf[mf][2][r], sf[mf][3][r]));
                    float vmax = fmaxf(fmaxf(t4[0], t4[1]), fmaxf(t4[2], t4[3]));
                    vmax = fmaxf(vmax, __shfl_xor(vmax, 16));
                    vmax = fmaxf(vmax, __shfl_xor(vmax, 32));
                    const bool norm = !__all(vmax <= mrun[mf] + 10.0f); // wave-uniform
                    float al = 1.0f;
                    if (norm) {
                        const float mnew = fmaxf(mrun[mf], vmax);
                        al = __builtin_amdgcn_exp2f(mrun[mf] - mnew);
                        mrun[mf] = mnew;
                    }
                    float s = 0.f;
#pragma unroll
                    for (int n = 0; n < 4; ++n) {
                        f32x4 p;
#pragma unroll
                        for (int r = 0; r < 4; ++r) p[r] = __builtin_amdgcn_exp2f(sf[mf][n][r] - mrun[mf]);
                        sf[mf][n] = p;
                        s += (p[0] + p[1]) + (p[2] + p[3]);
                    }
                    s += __shfl_xor(s, 16);
                    s += __shfl_xor(s, 32);
                    // P -> per-wave LDS (wave-internal ordering, no barrier)
#pragma unroll
                    for (int n = 0; n < 4; ++n) {
                        f16x4 pv;
#pragma unroll
                        for (int r = 0; r < 4; ++r) pv[r] = (f16)sf[mf][n][r];
                        *reinterpret_cast<f16x4*>(&Pl[w][mf * 16 + lr][n * 16 + lg * 4]) = pv;
                    }
                    if (norm) {
                        lsum[mf] = lsum[mf] * al + s;
#pragma unroll
                        for (int r = 0; r < 4; ++r) {
                            const float ar = __shfl(al, lg * 4 + r);
#pragma unroll
                            for (int n = 0; n < 4; ++n) zacc[mf][n][r] *= ar;
                        }
                    } else {
                        lsum[mf] += s;
                    }
                }
                // ---- Z += P V
#pragma unroll
                for (int kt = 0; kt < 2; ++kt) {
                    f16x8 pa[2];
#pragma unroll
                    for (int mf = 0; mf < 2; ++mf)
                        pa[mf] = *reinterpret_cast<const f16x8*>(&Pl[w][mf * 16 + lr][kt * 32 + lg * 8]);
                    __builtin_amdgcn_s_setprio(1);
#pragma unroll
                    for (int n = 0; n < 4; ++n)
#pragma unroll
                        for (int mf = 0; mf < 2; ++mf)
                            zacc[mf][n] = __builtin_amdgcn_mfma_f32_16x16x32_f16(pa[mf], vf[kt][n], zacc[mf][n], 0, 0, 0);
                    __builtin_amdgcn_s_setprio(0);
                }
            }
            __syncthreads(); // next buffer ready; protects buffer reuse
        }
        // ---- epilogue: divide by lsum (broadcast per row) and store
#pragma unroll
        for (int mf = 0; mf < 2; ++mf) {
            const float inv = 1.0f / lsum[mf];
#pragma unroll
            for (int r = 0; r < 4; ++r) {
                const float ir = __shfl(inv, lg * 4 + r);
#pragma unroll
                for (int n = 0; n < 4; ++n)
                    Z[base + (size_t)(wq0 + mf * 16 + lg * 4 + r) * D_ + n * 16 + lr] =
                        (f16)(zacc[mf][n][r] * ir);
            }
        }
    }
}

// ---------------------------------------------------------------- launcher
extern "C" void kernel_launch(void* const* d_in, const int* in_sizes, int n_in,
                              void* d_out, int out_size, void* d_ws, size_t ws_size,
                              hipStream_t stream) {
    const float* data    = (const float*)d_in[0];
    const float* context = (const float*)d_in[1];
    const float* Wq = (const float*)d_in[2];
    const float* bq = (const float*)d_in[3];
    const float* Wk = (const float*)d_in[4];
    const float* bk = (const float*)d_in[5];
    const float* Wv = (const float*)d_in[6];
    const float* bv = (const float*)d_in[7];
    const float* Wo = (const float*)d_in[8];
    const float* bo = (const float*)d_in[9];

    const size_t MD = (size_t)M_ * D_;
    const size_t DD = (size_t)D_ * D_;
    f16* dataB = (f16*)d_ws;
    f16* ctxB  = dataB + MD;
    f16* WqT   = ctxB + MD;
    f16* WkT   = WqT + DD;
    f16* WvT   = WkT + DD;
    f16* WoT   = WvT + DD;
    f16* Qb    = WoT + DD;
    f16* Kb    = Qb + MD;
    f16* VtB   = Kb + MD;  // [B][H][HD][S]
    f16* Zb    = VtB + MD;

    const int n4 = (int)(MD / 4);
    cvt_kernel<<<n4 / 256, 256, 0, stream>>>(data, dataB, n4);
    cvt_kernel<<<n4 / 256, 256, 0, stream>>>(context, ctxB, n4);
    dim3 tb(32, 8), tg(32, 32);
    transpose_cvt_kernel<<<tg, tb, 0, stream>>>(Wq, WqT);
    transpose_cvt_kernel<<<tg, tb, 0, stream>>>(Wk, WkT);
    transpose_cvt_kernel<<<tg, tb, 0, stream>>>(Wv, WvT);
    transpose_cvt_kernel<<<tg, tb, 0, stream>>>(Wo, WoT);

    dim3 gg(D_ / 128, M_ / 128); // (8, 64)
    gemm_bt<0, f16><<<gg, 256, 0, stream>>>(dataB, WqT, bq, Qb);
    gemm_bt<0, f16><<<gg, 256, 0, stream>>>(ctxB,  WkT, bk, Kb);
    gemm_bt<2, f16><<<gg, 256, 0, stream>>>(ctxB,  WvT, bv, VtB);

    attn_kernel<<<dim3(H_, B_, 8), 256, 0, stream>>>(Qb, Kb, VtB, Zb);

    gemm_bt<1, float><<<gg, 256, 0, stream>>>(Zb, WoT, bo, (float*)d_out);
}

// Round 8
// 203.755 us; speedup vs baseline: 1.9157x; 1.1234x over previous
//
#include <hip/hip_runtime.h>

// Problem constants
#define B_  4
#define S_  2048
#define D_  1024
#define H_  16
#define HD_ 64
#define M_  (B_*S_)   // 8192 rows total

typedef _Float16 f16;
typedef f16  f16x8 __attribute__((ext_vector_type(8)));
typedef f16  f16x4 __attribute__((ext_vector_type(4)));
typedef float f32x4 __attribute__((ext_vector_type(4)));

// global -> LDS direct DMA, 16B per lane. LDS dest = wave-uniform base + lane*16.
__device__ __forceinline__ void gload_lds16(const f16* g, f16* l) {
    __builtin_amdgcn_global_load_lds(
        (const __attribute__((address_space(1))) void*)g,
        (__attribute__((address_space(3))) void*)l, 16, 0, 0);
}

// ---------------------------------------------------------------- converts (fused: data+context)
__global__ __launch_bounds__(256) void cvt2_kernel(const float* __restrict__ a,
                                                   const float* __restrict__ c,
                                                   f16* __restrict__ out, int n4each) {
    int i = blockIdx.x * 256 + threadIdx.x;
    const float* src = (i < n4each) ? a : c;
    int j = (i < n4each) ? i : i - n4each;
    f32x4 v = *reinterpret_cast<const f32x4*>(src + (size_t)j * 4);
    *reinterpret_cast<f16x4*>(out + (size_t)i * 4) = __builtin_convertvector(v, f16x4);
}

// all four weights W[K][N] f32 -> WT[N][K] f16 (outputs contiguous per z)
__global__ __launch_bounds__(256) void transpose_cvt4_kernel(const float* __restrict__ Wq,
                                                             const float* __restrict__ Wk,
                                                             const float* __restrict__ Wv,
                                                             const float* __restrict__ Wo,
                                                             f16* __restrict__ WT) {
    __shared__ float tile[32][33];
    const int z = blockIdx.z;
    const float* W = (z == 0) ? Wq : (z == 1) ? Wk : (z == 2) ? Wv : Wo;
    f16* dst = WT + (size_t)z * D_ * D_;
    const int n0 = blockIdx.x * 32, k0 = blockIdx.y * 32;
    const int tx = threadIdx.x & 31, ty = threadIdx.x >> 5; // (32,8)
#pragma unroll
    for (int j = 0; j < 4; ++j)
        tile[ty + 8 * j][tx] = W[(size_t)(k0 + ty + 8 * j) * D_ + n0 + tx];
    __syncthreads();
#pragma unroll
    for (int j = 0; j < 4; ++j)
        dst[(size_t)(n0 + ty + 8 * j) * D_ + k0 + tx] = (f16)tile[tx][ty + 8 * j];
}

// ---------------------------------------------------------------- fused QKV GEMM
// grid (24, 64): seg = x>>3 (0=Q,1=K,2=V). A = data (Q) or context (K,V).
// Wt = WqT base; WqT/WkT/WvT contiguous -> 3072 B^T columns. 128x128 tile, BK=32.
// Counted-vmcnt double-buffer: stage(t+1) stays in flight across the barrier.
__global__ __launch_bounds__(256) void gemm_qkv(const f16* __restrict__ Adata,
                                                const f16* __restrict__ Actx,
                                                const f16* __restrict__ Wt,
                                                const float* __restrict__ bq,
                                                const float* __restrict__ bk,
                                                const float* __restrict__ bv,
                                                f16* __restrict__ Qb,
                                                f16* __restrict__ Kb,
                                                f16* __restrict__ VtB) {
    constexpr int K = D_;
    constexpr int NT = K / 32;
    __shared__ __align__(16) f16 Al[2][128 * 32];
    __shared__ __align__(16) f16 Bl[2][128 * 32];
    const int nx = blockIdx.x, seg = nx >> 3;
    const f16* __restrict__ A = seg ? Actx : Adata;
    const int m0 = blockIdx.y * 128, n0 = nx * 128;
    const int tid = threadIdx.x;
    const int w = tid >> 6, l = tid & 63, lr = l & 15, lg = l >> 4;
    const int wr = w >> 1, wc = w & 1;
    const int srow = tid >> 2, soff = (tid & 3) * 8;

    auto stage = [&](int buf, int kk) {
#pragma unroll
        for (int i = 0; i < 2; ++i) {
            const int row = srow + i * 64;
            gload_lds16(A  + (size_t)(m0 + row) * K + kk + soff, &Al[buf][(w + 4 * i) * 512]);
            gload_lds16(Wt + (size_t)(n0 + row) * K + kk + soff, &Bl[buf][(w + 4 * i) * 512]);
        }
    };

    f32x4 acc[4][4] = {};
    stage(0, 0);
    for (int t = 0; t < NT; ++t) {
        const int buf = t & 1;
        if (t + 1 < NT) {
            stage(buf ^ 1, (t + 1) * 32);
            asm volatile("s_waitcnt vmcnt(4)" ::: "memory"); // stage(t) landed; stage(t+1) in flight
        } else {
            asm volatile("s_waitcnt vmcnt(0)" ::: "memory");
        }
        __builtin_amdgcn_s_barrier();
        f16x8 a[4], b[4];
#pragma unroll
        for (int m = 0; m < 4; ++m)
            a[m] = *reinterpret_cast<const f16x8*>(&Al[buf][(wr * 64 + m * 16 + lr) * 32 + lg * 8]);
#pragma unroll
        for (int n = 0; n < 4; ++n)
            b[n] = *reinterpret_cast<const f16x8*>(&Bl[buf][(wc * 64 + n * 16 + lr) * 32 + lg * 8]);
        __builtin_amdgcn_s_setprio(1);
#pragma unroll
        for (int m = 0; m < 4; ++m)
#pragma unroll
            for (int n = 0; n < 4; ++n)
                acc[m][n] = __builtin_amdgcn_mfma_f32_16x16x32_f16(a[m], b[n], acc[m][n], 0, 0, 0);
        __builtin_amdgcn_s_setprio(0);
        __builtin_amdgcn_s_barrier(); // protect buf reuse (readers done before next stage of this buf)
    }
    const float* bias = (seg == 0) ? bq : (seg == 1) ? bk : bv;
#pragma unroll
    for (int n = 0; n < 4; ++n) {
        const int col = n0 + wc * 64 + n * 16 + lr;       // 0..3071
        const int lc = col - seg * 1024;                  // 0..1023 within segment
        const float bvv = bias[lc];
#pragma unroll
        for (int m = 0; m < 4; ++m) {
            const int row = m0 + wr * 64 + m * 16 + lg * 4;
            if (seg == 2) { // V: write transposed VT[B][H*HD][S]
                const int bb = row >> 11, s0 = row & 2047;
                f16x4 v;
#pragma unroll
                for (int r = 0; r < 4; ++r) v[r] = (f16)(acc[m][n][r] + bvv);
                *reinterpret_cast<f16x4*>(VtB + ((size_t)(bb * D_ + lc)) * S_ + s0) = v;
            } else {
                f16* dst = (seg == 0) ? Qb : Kb;
#pragma unroll
                for (int r = 0; r < 4; ++r)
                    dst[(size_t)(row + r) * D_ + lc] = (f16)(acc[m][n][r] + bvv);
            }
        }
    }
}

// ---------------------------------------------------------------- output GEMM  C = A @ Bt^T + bias (f32 out)
__global__ __launch_bounds__(256) void gemm_out(const f16* __restrict__ A,
                                                const f16* __restrict__ Bt,
                                                const float* __restrict__ bias,
                                                float* __restrict__ C) {
    constexpr int K = D_;
    constexpr int NT = K / 32;
    __shared__ __align__(16) f16 Al[2][128 * 32];
    __shared__ __align__(16) f16 Bl[2][128 * 32];
    const int m0 = blockIdx.y * 128, n0 = blockIdx.x * 128;
    const int tid = threadIdx.x;
    const int w = tid >> 6, l = tid & 63, lr = l & 15, lg = l >> 4;
    const int wr = w >> 1, wc = w & 1;
    const int srow = tid >> 2, soff = (tid & 3) * 8;

    auto stage = [&](int buf, int kk) {
#pragma unroll
        for (int i = 0; i < 2; ++i) {
            const int row = srow + i * 64;
            gload_lds16(A  + (size_t)(m0 + row) * K + kk + soff, &Al[buf][(w + 4 * i) * 512]);
            gload_lds16(Bt + (size_t)(n0 + row) * K + kk + soff, &Bl[buf][(w + 4 * i) * 512]);
        }
    };

    f32x4 acc[4][4] = {};
    stage(0, 0);
    for (int t = 0; t < NT; ++t) {
        const int buf = t & 1;
        if (t + 1 < NT) {
            stage(buf ^ 1, (t + 1) * 32);
            asm volatile("s_waitcnt vmcnt(4)" ::: "memory");
        } else {
            asm volatile("s_waitcnt vmcnt(0)" ::: "memory");
        }
        __builtin_amdgcn_s_barrier();
        f16x8 a[4], b[4];
#pragma unroll
        for (int m = 0; m < 4; ++m)
            a[m] = *reinterpret_cast<const f16x8*>(&Al[buf][(wr * 64 + m * 16 + lr) * 32 + lg * 8]);
#pragma unroll
        for (int n = 0; n < 4; ++n)
            b[n] = *reinterpret_cast<const f16x8*>(&Bl[buf][(wc * 64 + n * 16 + lr) * 32 + lg * 8]);
        __builtin_amdgcn_s_setprio(1);
#pragma unroll
        for (int m = 0; m < 4; ++m)
#pragma unroll
            for (int n = 0; n < 4; ++n)
                acc[m][n] = __builtin_amdgcn_mfma_f32_16x16x32_f16(a[m], b[n], acc[m][n], 0, 0, 0);
        __builtin_amdgcn_s_setprio(0);
        __builtin_amdgcn_s_barrier();
    }
#pragma unroll
    for (int n = 0; n < 4; ++n) {
        const int col = n0 + wc * 64 + n * 16 + lr;
        const float bv = bias[col];
#pragma unroll
        for (int m = 0; m < 4; ++m) {
            const int row = m0 + wr * 64 + m * 16 + lg * 4;
#pragma unroll
            for (int r = 0; r < 4; ++r)
                C[(size_t)(row + r) * D_ + col] = acc[m][n][r] + bv;
        }
    }
}

// ---------------------------------------------------------------- causal flash attention
// grid (H, B, 8), 256 threads = 4 waves. Block handles q-tiles {15-pp, pp}.
// K,V staged to LDS via global_load_lds, double-buffered, XOR-swizzled both sides.
// Counted vmcnt(4): stage(t+1) stays in flight across the barrier (no drain).
// Swapped QK^T (lane owns q-row's scores), defer-max, P via per-wave LDS.
__global__ __launch_bounds__(256, 2) void attn_kernel(const f16* __restrict__ Q,
                                                      const f16* __restrict__ Kg,
                                                      const f16* __restrict__ Vt,
                                                      f16* __restrict__ Z) {
    __shared__ __align__(16) f16 KL[2][64 * 64];
    __shared__ __align__(16) f16 VL[2][64 * 64];
    __shared__ __align__(16) f16 Pl[4][32][72];
    const int h = blockIdx.x, b = blockIdx.y, pp = blockIdx.z;
    const int tid = threadIdx.x, w = tid >> 6, l = tid & 63, lr = l & 15, lg = l >> 4;
    const size_t base   = ((size_t)b * S_) * D_ + h * HD_;
    const size_t vtbase = ((size_t)(b * D_ + h * HD_)) * S_;
    const f16* __restrict__ Kbase = Kg + base;
    const f16* __restrict__ Vbase = Vt + vtbase;
    const float sc = 0.125f * 1.44269504f;
    const int sw_xor = lr & 7;

    auto stageKV = [&](int buf, int t0) {
#pragma unroll
        for (int i = 0; i < 2; ++i) {
            const int c = i * 256 + tid;
            const int row = c >> 3, g16 = (c & 7) ^ (row & 7);
            f16* dstK = &KL[buf][(i * 256 + w * 64) * 8];
            f16* dstV = &VL[buf][(i * 256 + w * 64) * 8];
            gload_lds16(Kbase + (size_t)(t0 + row) * D_ + g16 * 8, dstK);
            gload_lds16(Vbase + (size_t)row * S_ + t0 + g16 * 8, dstV);
        }
    };

    for (int half = 0; half < 2; ++half) {
        const int qt = half ? pp : (15 - pp);
        const int q0 = qt * 128, wq0 = q0 + w * 32;
        const int ntw = ((wq0 + 31) >> 6) + 1;
        const int ntb = qt * 2 + 2;

        f16x8 qf[2][2];
#pragma unroll
        for (int mf = 0; mf < 2; ++mf)
#pragma unroll
            for (int kd = 0; kd < 2; ++kd)
                qf[mf][kd] = *reinterpret_cast<const f16x8*>(
                    Q + base + (size_t)(wq0 + mf * 16 + lr) * D_ + kd * 32 + lg * 8);

        f32x4 zacc[2][4] = {};
        float mrun[2] = {-3.0e38f, -3.0e38f}, lsum[2] = {0.f, 0.f};

        stageKV(0, 0);
        for (int t = 0; t < ntb; ++t) {
            const int buf = t & 1;
            if (t + 1 < ntb) {
                stageKV(buf ^ 1, (t + 1) * 64);
                asm volatile("s_waitcnt vmcnt(4)" ::: "memory"); // stage(t) landed
            } else {
                asm volatile("s_waitcnt vmcnt(0)" ::: "memory");
            }
            __builtin_amdgcn_s_barrier();
            if (t < ntw) {
                const int t0 = t * 64;
                f16x8 kf[2][4];
#pragma unroll
                for (int kd = 0; kd < 2; ++kd)
#pragma unroll
                    for (int n = 0; n < 4; ++n)
                        kf[kd][n] = *reinterpret_cast<const f16x8*>(
                            &KL[buf][(n * 16 + lr) * 64 + (((kd * 4 + lg) ^ sw_xor) * 8)]);
                f32x4 sf[2][4] = {};
                __builtin_amdgcn_s_setprio(1);
#pragma unroll
                for (int kd = 0; kd < 2; ++kd)
#pragma unroll
                    for (int n = 0; n < 4; ++n)
#pragma unroll
                        for (int mf = 0; mf < 2; ++mf)
                            sf[mf][n] = __builtin_amdgcn_mfma_f32_16x16x32_f16(kf[kd][n], qf[mf][kd], sf[mf][n], 0, 0, 0);
                __builtin_amdgcn_s_setprio(0);
                f16x8 vf[2][4];
#pragma unroll
                for (int kt = 0; kt < 2; ++kt)
#pragma unroll
                    for (int n = 0; n < 4; ++n)
                        vf[kt][n] = *reinterpret_cast<const f16x8*>(
                            &VL[buf][(n * 16 + lr) * 64 + (((kt * 4 + lg) ^ sw_xor) * 8)]);
                if (t == ntw - 1) {
#pragma unroll
                    for (int mf = 0; mf < 2; ++mf)
#pragma unroll
                        for (int n = 0; n < 4; ++n)
#pragma unroll
                            for (int r = 0; r < 4; ++r) {
                                const bool masked = (t0 + n * 16 + lg * 4 + r) > (wq0 + mf * 16 + lr);
                                sf[mf][n][r] = masked ? -3.0e38f : sf[mf][n][r] * sc;
                            }
                } else {
#pragma unroll
                    for (int mf = 0; mf < 2; ++mf)
#pragma unroll
                        for (int n = 0; n < 4; ++n)
#pragma unroll
                            for (int r = 0; r < 4; ++r) sf[mf][n][r] *= sc;
                }
#pragma unroll
                for (int mf = 0; mf < 2; ++mf) {
                    f32x4 t4;
#pragma unroll
                    for (int r = 0; r < 4; ++r)
                        t4[r] = fmaxf(fmaxf(sf[mf][0][r], sf[mf][1][r]), fmaxf(sf[mf][2][r], sf[mf][3][r]));
                    float vmax = fmaxf(fmaxf(t4[0], t4[1]), fmaxf(t4[2], t4[3]));
                    vmax = fmaxf(vmax, __shfl_xor(vmax, 16));
                    vmax = fmaxf(vmax, __shfl_xor(vmax, 32));
                    const bool norm = !__all(vmax <= mrun[mf] + 10.0f);
                    float al = 1.0f;
                    if (norm) {
                        const float mnew = fmaxf(mrun[mf], vmax);
                        al = __builtin_amdgcn_exp2f(mrun[mf] - mnew);
                        mrun[mf] = mnew;
                    }
                    float s = 0.f;
#pragma unroll
                    for (int n = 0; n < 4; ++n) {
                        f32x4 p;
#pragma unroll
                        for (int r = 0; r < 4; ++r) p[r] = __builtin_amdgcn_exp2f(sf[mf][n][r] - mrun[mf]);
                        sf[mf][n] = p;
                        s += (p[0] + p[1]) + (p[2] + p[3]);
                    }
                    s += __shfl_xor(s, 16);
                    s += __shfl_xor(s, 32);
#pragma unroll
                    for (int n = 0; n < 4; ++n) {
                        f16x4 pv;
#pragma unroll
                        for (int r = 0; r < 4; ++r) pv[r] = (f16)sf[mf][n][r];
                        *reinterpret_cast<f16x4*>(&Pl[w][mf * 16 + lr][n * 16 + lg * 4]) = pv;
                    }
                    if (norm) {
                        lsum[mf] = lsum[mf] * al + s;
#pragma unroll
                        for (int r = 0; r < 4; ++r) {
                            const float ar = __shfl(al, lg * 4 + r);
#pragma unroll
                            for (int n = 0; n < 4; ++n) zacc[mf][n][r] *= ar;
                        }
                    } else {
                        lsum[mf] += s;
                    }
                }
#pragma unroll
                for (int kt = 0; kt < 2; ++kt) {
                    f16x8 pa[2];
#pragma unroll
                    for (int mf = 0; mf < 2; ++mf)
                        pa[mf] = *reinterpret_cast<const f16x8*>(&Pl[w][mf * 16 + lr][kt * 32 + lg * 8]);
                    __builtin_amdgcn_s_setprio(1);
#pragma unroll
                    for (int n = 0; n < 4; ++n)
#pragma unroll
                        for (int mf = 0; mf < 2; ++mf)
                            zacc[mf][n] = __builtin_amdgcn_mfma_f32_16x16x32_f16(pa[mf], vf[kt][n], zacc[mf][n], 0, 0, 0);
                    __builtin_amdgcn_s_setprio(0);
                }
            }
            __builtin_amdgcn_s_barrier(); // buffer-reuse protection
        }
#pragma unroll
        for (int mf = 0; mf < 2; ++mf) {
            const float inv = 1.0f / lsum[mf];
#pragma unroll
            for (int r = 0; r < 4; ++r) {
                const float ir = __shfl(inv, lg * 4 + r);
#pragma unroll
                for (int n = 0; n < 4; ++n)
                    Z[base + (size_t)(wq0 + mf * 16 + lg * 4 + r) * D_ + n * 16 + lr] =
                        (f16)(zacc[mf][n][r] * ir);
            }
        }
    }
}

// ---------------------------------------------------------------- launcher
extern "C" void kernel_launch(void* const* d_in, const int* in_sizes, int n_in,
                              void* d_out, int out_size, void* d_ws, size_t ws_size,
                              hipStream_t stream) {
    const float* data    = (const float*)d_in[0];
    const float* context = (const float*)d_in[1];
    const float* Wq = (const float*)d_in[2];
    const float* bq = (const float*)d_in[3];
    const float* Wk = (const float*)d_in[4];
    const float* bk = (const float*)d_in[5];
    const float* Wv = (const float*)d_in[6];
    const float* bv = (const float*)d_in[7];
    const float* Wo = (const float*)d_in[8];
    const float* bo = (const float*)d_in[9];

    const size_t MD = (size_t)M_ * D_;
    const size_t DD = (size_t)D_ * D_;
    f16* dataB = (f16*)d_ws;
    f16* ctxB  = dataB + MD;
    f16* WqT   = ctxB + MD;   // WqT,WkT,WvT,WoT contiguous (3072+1024 cols of B^T)
    f16* WkT   = WqT + DD;
    f16* WvT   = WkT + DD;
    f16* WoT   = WvT + DD;
    f16* Qb    = WoT + DD;
    f16* Kb    = Qb + MD;
    f16* VtB   = Kb + MD;     // [B][H][HD][S]
    f16* Zb    = VtB + MD;

    const int n4 = (int)(MD / 4);
    cvt2_kernel<<<2 * n4 / 256, 256, 0, stream>>>(data, context, dataB, n4);
    transpose_cvt4_kernel<<<dim3(32, 32, 4), 256, 0, stream>>>(Wq, Wk, Wv, Wo, WqT);

    gemm_qkv<<<dim3(24, 64), 256, 0, stream>>>(dataB, ctxB, WqT, bq, bk, bv, Qb, Kb, VtB);

    attn_kernel<<<dim3(H_, B_, 8), 256, 0, stream>>>(Qb, Kb, VtB, Zb);

    gemm_out<<<dim3(8, 64), 256, 0, stream>>>(Zb, WoT, bo, (float*)d_out);
}

// Round 9
// 200.913 us; speedup vs baseline: 1.9428x; 1.0141x over previous
//
#include <hip/hip_runtime.h>

// Problem constants
#define B_  4
#define S_  2048
#define D_  1024
#define H_  16
#define HD_ 64
#define M_  (B_*S_)   // 8192 rows total

typedef _Float16 f16;
typedef f16  f16x8 __attribute__((ext_vector_type(8)));
typedef f16  f16x4 __attribute__((ext_vector_type(4)));
typedef float f32x4 __attribute__((ext_vector_type(4)));

// global -> LDS direct DMA, 16B per lane. LDS dest = wave-uniform base + lane*16.
__device__ __forceinline__ void gload_lds16(const f16* g, f16* l) {
    __builtin_amdgcn_global_load_lds(
        (const __attribute__((address_space(1))) void*)g,
        (__attribute__((address_space(3))) void*)l, 16, 0, 0);
}

// ---------------------------------------------------------------- converts (fused: data+context)
__global__ __launch_bounds__(256) void cvt2_kernel(const float* __restrict__ a,
                                                   const float* __restrict__ c,
                                                   f16* __restrict__ out, int n4each) {
    int i = blockIdx.x * 256 + threadIdx.x;
    const float* src = (i < n4each) ? a : c;
    int j = (i < n4each) ? i : i - n4each;
    f32x4 v = *reinterpret_cast<const f32x4*>(src + (size_t)j * 4);
    *reinterpret_cast<f16x4*>(out + (size_t)i * 4) = __builtin_convertvector(v, f16x4);
}

// all four weights W[K][N] f32 -> WT[N][K] f16 (outputs contiguous per z)
__global__ __launch_bounds__(256) void transpose_cvt4_kernel(const float* __restrict__ Wq,
                                                             const float* __restrict__ Wk,
                                                             const float* __restrict__ Wv,
                                                             const float* __restrict__ Wo,
                                                             f16* __restrict__ WT) {
    __shared__ float tile[32][33];
    const int z = blockIdx.z;
    const float* W = (z == 0) ? Wq : (z == 1) ? Wk : (z == 2) ? Wv : Wo;
    f16* dst = WT + (size_t)z * D_ * D_;
    const int n0 = blockIdx.x * 32, k0 = blockIdx.y * 32;
    const int tx = threadIdx.x & 31, ty = threadIdx.x >> 5; // (32,8)
#pragma unroll
    for (int j = 0; j < 4; ++j)
        tile[ty + 8 * j][tx] = W[(size_t)(k0 + ty + 8 * j) * D_ + n0 + tx];
    __syncthreads();
#pragma unroll
    for (int j = 0; j < 4; ++j)
        dst[(size_t)(n0 + ty + 8 * j) * D_ + k0 + tx] = (f16)tile[tx][ty + 8 * j];
}

// ---------------------------------------------------------------- fused QKV GEMM
// XCD-chunked remap: HW runs linear id on XCD id%8; we re-index work so XCD j owns
// row-panels wy in [8j, 8j+8) -> each A panel is fetched by ONE XCD's L2 (was 8x).
// seg = wx>>3 (0=Q,1=K,2=V); Wt = WqT base (WqT/WkT/WvT contiguous, 3072 cols).
// Counted-vmcnt double-buffer: stage(t+1) stays in flight across the barrier.
__global__ __launch_bounds__(256) void gemm_qkv(const f16* __restrict__ Adata,
                                                const f16* __restrict__ Actx,
                                                const f16* __restrict__ Wt,
                                                const float* __restrict__ bq,
                                                const float* __restrict__ bk,
                                                const float* __restrict__ bv,
                                                f16* __restrict__ Qb,
                                                f16* __restrict__ Kb,
                                                f16* __restrict__ VtB) {
    constexpr int K = D_;
    constexpr int NT = K / 32;
    __shared__ __align__(16) f16 Al[2][128 * 32];
    __shared__ __align__(16) f16 Bl[2][128 * 32];
    // XCD-chunked work remap (grid 24 x 64 = 1536 blocks, 192 per XCD)
    const int id = (int)(blockIdx.y * 24 + blockIdx.x);
    const int work = (id & 7) * 192 + (id >> 3);
    const int wy = work / 24, wx = work - wy * 24;
    const int seg = wx >> 3;
    const f16* __restrict__ A = seg ? Actx : Adata;
    const int m0 = wy * 128, n0 = wx * 128;
    const int tid = threadIdx.x;
    const int w = tid >> 6, l = tid & 63, lr = l & 15, lg = l >> 4;
    const int wr = w >> 1, wc = w & 1;
    const int srow = tid >> 2, soff = (tid & 3) * 8;

    auto stage = [&](int buf, int kk) {
#pragma unroll
        for (int i = 0; i < 2; ++i) {
            const int row = srow + i * 64;
            gload_lds16(A  + (size_t)(m0 + row) * K + kk + soff, &Al[buf][(w + 4 * i) * 512]);
            gload_lds16(Wt + (size_t)(n0 + row) * K + kk + soff, &Bl[buf][(w + 4 * i) * 512]);
        }
    };

    f32x4 acc[4][4] = {};
    stage(0, 0);
    for (int t = 0; t < NT; ++t) {
        const int buf = t & 1;
        if (t + 1 < NT) {
            stage(buf ^ 1, (t + 1) * 32);
            asm volatile("s_waitcnt vmcnt(4)" ::: "memory"); // stage(t) landed; stage(t+1) in flight
        } else {
            asm volatile("s_waitcnt vmcnt(0)" ::: "memory");
        }
        __builtin_amdgcn_s_barrier();
        f16x8 a[4], b[4];
#pragma unroll
        for (int m = 0; m < 4; ++m)
            a[m] = *reinterpret_cast<const f16x8*>(&Al[buf][(wr * 64 + m * 16 + lr) * 32 + lg * 8]);
#pragma unroll
        for (int n = 0; n < 4; ++n)
            b[n] = *reinterpret_cast<const f16x8*>(&Bl[buf][(wc * 64 + n * 16 + lr) * 32 + lg * 8]);
        __builtin_amdgcn_s_setprio(1);
#pragma unroll
        for (int m = 0; m < 4; ++m)
#pragma unroll
            for (int n = 0; n < 4; ++n)
                acc[m][n] = __builtin_amdgcn_mfma_f32_16x16x32_f16(a[m], b[n], acc[m][n], 0, 0, 0);
        __builtin_amdgcn_s_setprio(0);
        __builtin_amdgcn_s_barrier(); // protect buf reuse
    }
    const float* bias = (seg == 0) ? bq : (seg == 1) ? bk : bv;
#pragma unroll
    for (int n = 0; n < 4; ++n) {
        const int col = n0 + wc * 64 + n * 16 + lr;       // 0..3071
        const int lc = col - seg * 1024;                  // 0..1023 within segment
        const float bvv = bias[lc];
#pragma unroll
        for (int m = 0; m < 4; ++m) {
            const int row = m0 + wr * 64 + m * 16 + lg * 4;
            if (seg == 2) { // V: write transposed VT[B][H*HD][S]
                const int bb = row >> 11, s0 = row & 2047;
                f16x4 v;
#pragma unroll
                for (int r = 0; r < 4; ++r) v[r] = (f16)(acc[m][n][r] + bvv);
                *reinterpret_cast<f16x4*>(VtB + ((size_t)(bb * D_ + lc)) * S_ + s0) = v;
            } else {
                f16* dst = (seg == 0) ? Qb : Kb;
#pragma unroll
                for (int r = 0; r < 4; ++r)
                    dst[(size_t)(row + r) * D_ + lc] = (f16)(acc[m][n][r] + bvv);
            }
        }
    }
}

// ---------------------------------------------------------------- output GEMM  C = A @ Bt^T + bias (f32 out)
// Same XCD-chunked remap: grid 8 x 64 = 512 blocks, 64 per XCD; XCD j owns wy in [8j,8j+8).
__global__ __launch_bounds__(256) void gemm_out(const f16* __restrict__ A,
                                                const f16* __restrict__ Bt,
                                                const float* __restrict__ bias,
                                                float* __restrict__ C) {
    constexpr int K = D_;
    constexpr int NT = K / 32;
    __shared__ __align__(16) f16 Al[2][128 * 32];
    __shared__ __align__(16) f16 Bl[2][128 * 32];
    const int id = (int)(blockIdx.y * 8 + blockIdx.x);
    const int work = (id & 7) * 64 + (id >> 3);
    const int wy = work >> 3, wx = work & 7;
    const int m0 = wy * 128, n0 = wx * 128;
    const int tid = threadIdx.x;
    const int w = tid >> 6, l = tid & 63, lr = l & 15, lg = l >> 4;
    const int wr = w >> 1, wc = w & 1;
    const int srow = tid >> 2, soff = (tid & 3) * 8;

    auto stage = [&](int buf, int kk) {
#pragma unroll
        for (int i = 0; i < 2; ++i) {
            const int row = srow + i * 64;
            gload_lds16(A  + (size_t)(m0 + row) * K + kk + soff, &Al[buf][(w + 4 * i) * 512]);
            gload_lds16(Bt + (size_t)(n0 + row) * K + kk + soff, &Bl[buf][(w + 4 * i) * 512]);
        }
    };

    f32x4 acc[4][4] = {};
    stage(0, 0);
    for (int t = 0; t < NT; ++t) {
        const int buf = t & 1;
        if (t + 1 < NT) {
            stage(buf ^ 1, (t + 1) * 32);
            asm volatile("s_waitcnt vmcnt(4)" ::: "memory");
        } else {
            asm volatile("s_waitcnt vmcnt(0)" ::: "memory");
        }
        __builtin_amdgcn_s_barrier();
        f16x8 a[4], b[4];
#pragma unroll
        for (int m = 0; m < 4; ++m)
            a[m] = *reinterpret_cast<const f16x8*>(&Al[buf][(wr * 64 + m * 16 + lr) * 32 + lg * 8]);
#pragma unroll
        for (int n = 0; n < 4; ++n)
            b[n] = *reinterpret_cast<const f16x8*>(&Bl[buf][(wc * 64 + n * 16 + lr) * 32 + lg * 8]);
        __builtin_amdgcn_s_setprio(1);
#pragma unroll
        for (int m = 0; m < 4; ++m)
#pragma unroll
            for (int n = 0; n < 4; ++n)
                acc[m][n] = __builtin_amdgcn_mfma_f32_16x16x32_f16(a[m], b[n], acc[m][n], 0, 0, 0);
        __builtin_amdgcn_s_setprio(0);
        __builtin_amdgcn_s_barrier();
    }
#pragma unroll
    for (int n = 0; n < 4; ++n) {
        const int col = n0 + wc * 64 + n * 16 + lr;
        const float bv = bias[col];
#pragma unroll
        for (int m = 0; m < 4; ++m) {
            const int row = m0 + wr * 64 + m * 16 + lg * 4;
#pragma unroll
            for (int r = 0; r < 4; ++r)
                C[(size_t)(row + r) * D_ + col] = acc[m][n][r] + bv;
        }
    }
}

// ---------------------------------------------------------------- causal flash attention
// grid (H, B, 8), 256 threads = 4 waves. Block handles q-tiles {15-pp, pp}.
// (id%8 = h%8 -> all blocks of one (b,h) already share an XCD for K/V L2 reuse.)
// K,V staged to LDS via global_load_lds, double-buffered, XOR-swizzled both sides.
// Counted vmcnt(4). Swapped QK^T; softmax in scaled-log2 domain with the scale
// fused into the exp FMA (no separate scale pass); defer-max; P via per-wave LDS.
__global__ __launch_bounds__(256, 2) void attn_kernel(const f16* __restrict__ Q,
                                                      const f16* __restrict__ Kg,
                                                      const f16* __restrict__ Vt,
                                                      f16* __restrict__ Z) {
    __shared__ __align__(16) f16 KL[2][64 * 64];
    __shared__ __align__(16) f16 VL[2][64 * 64];
    __shared__ __align__(16) f16 Pl[4][32][72];
    const int h = blockIdx.x, b = blockIdx.y, pp = blockIdx.z;
    const int tid = threadIdx.x, w = tid >> 6, l = tid & 63, lr = l & 15, lg = l >> 4;
    const size_t base   = ((size_t)b * S_) * D_ + h * HD_;
    const size_t vtbase = ((size_t)(b * D_ + h * HD_)) * S_;
    const f16* __restrict__ Kbase = Kg + base;
    const f16* __restrict__ Vbase = Vt + vtbase;
    const float sc = 0.125f * 1.44269504f; // 1/sqrt(64) * log2(e)
    const int sw_xor = lr & 7;

    auto stageKV = [&](int buf, int t0) {
#pragma unroll
        for (int i = 0; i < 2; ++i) {
            const int c = i * 256 + tid;
            const int row = c >> 3, g16 = (c & 7) ^ (row & 7);
            f16* dstK = &KL[buf][(i * 256 + w * 64) * 8];
            f16* dstV = &VL[buf][(i * 256 + w * 64) * 8];
            gload_lds16(Kbase + (size_t)(t0 + row) * D_ + g16 * 8, dstK);
            gload_lds16(Vbase + (size_t)row * S_ + t0 + g16 * 8, dstV);
        }
    };

    for (int half = 0; half < 2; ++half) {
        const int qt = half ? pp : (15 - pp);
        const int q0 = qt * 128, wq0 = q0 + w * 32;
        const int ntw = ((wq0 + 31) >> 6) + 1;
        const int ntb = qt * 2 + 2;

        f16x8 qf[2][2];
#pragma unroll
        for (int mf = 0; mf < 2; ++mf)
#pragma unroll
            for (int kd = 0; kd < 2; ++kd)
                qf[mf][kd] = *reinterpret_cast<const f16x8*>(
                    Q + base + (size_t)(wq0 + mf * 16 + lr) * D_ + kd * 32 + lg * 8);

        f32x4 zacc[2][4] = {};
        float mrun[2] = {-3.0e38f, -3.0e38f}, lsum[2] = {0.f, 0.f};

        stageKV(0, 0);
        for (int t = 0; t < ntb; ++t) {
            const int buf = t & 1;
            if (t + 1 < ntb) {
                stageKV(buf ^ 1, (t + 1) * 64);
                asm volatile("s_waitcnt vmcnt(4)" ::: "memory"); // stage(t) landed
            } else {
                asm volatile("s_waitcnt vmcnt(0)" ::: "memory");
            }
            __builtin_amdgcn_s_barrier();
            if (t < ntw) {
                const int t0 = t * 64;
                f16x8 kf[2][4];
#pragma unroll
                for (int kd = 0; kd < 2; ++kd)
#pragma unroll
                    for (int n = 0; n < 4; ++n)
                        kf[kd][n] = *reinterpret_cast<const f16x8*>(
                            &KL[buf][(n * 16 + lr) * 64 + (((kd * 4 + lg) ^ sw_xor) * 8)]);
                f32x4 sf[2][4] = {};
                __builtin_amdgcn_s_setprio(1);
#pragma unroll
                for (int kd = 0; kd < 2; ++kd)
#pragma unroll
                    for (int n = 0; n < 4; ++n)
#pragma unroll
                        for (int mf = 0; mf < 2; ++mf)
                            sf[mf][n] = __builtin_amdgcn_mfma_f32_16x16x32_f16(kf[kd][n], qf[mf][kd], sf[mf][n], 0, 0, 0);
                __builtin_amdgcn_s_setprio(0);
                f16x8 vf[2][4];
#pragma unroll
                for (int kt = 0; kt < 2; ++kt)
#pragma unroll
                    for (int n = 0; n < 4; ++n)
                        vf[kt][n] = *reinterpret_cast<const f16x8*>(
                            &VL[buf][(n * 16 + lr) * 64 + (((kt * 4 + lg) ^ sw_xor) * 8)]);
                // mask only (raw scores); scale folds into the exp FMA below
                if (t == ntw - 1) {
#pragma unroll
                    for (int mf = 0; mf < 2; ++mf)
#pragma unroll
                        for (int n = 0; n < 4; ++n)
#pragma unroll
                            for (int r = 0; r < 4; ++r)
                                if ((t0 + n * 16 + lg * 4 + r) > (wq0 + mf * 16 + lr))
                                    sf[mf][n][r] = -3.0e38f;
                }
#pragma unroll
                for (int mf = 0; mf < 2; ++mf) {
                    f32x4 t4;
#pragma unroll
                    for (int r = 0; r < 4; ++r)
                        t4[r] = fmaxf(fmaxf(sf[mf][0][r], sf[mf][1][r]), fmaxf(sf[mf][2][r], sf[mf][3][r]));
                    float vmax = fmaxf(fmaxf(t4[0], t4[1]), fmaxf(t4[2], t4[3]));
                    vmax = fmaxf(vmax, __shfl_xor(vmax, 16));
                    vmax = fmaxf(vmax, __shfl_xor(vmax, 32));
                    const float vs = vmax * sc; // scaled-domain tile max
                    const bool norm = !__all(vs <= mrun[mf] + 10.0f);
                    float al = 1.0f;
                    if (norm) {
                        const float mnew = fmaxf(mrun[mf], vs);
                        al = __builtin_amdgcn_exp2f(mrun[mf] - mnew);
                        mrun[mf] = mnew;
                    }
                    float s = 0.f;
#pragma unroll
                    for (int n = 0; n < 4; ++n) {
                        f32x4 p;
#pragma unroll
                        for (int r = 0; r < 4; ++r)
                            p[r] = __builtin_amdgcn_exp2f(fmaf(sf[mf][n][r], sc, -mrun[mf]));
                        sf[mf][n] = p;
                        s += (p[0] + p[1]) + (p[2] + p[3]);
                    }
                    s += __shfl_xor(s, 16);
                    s += __shfl_xor(s, 32);
#pragma unroll
                    for (int n = 0; n < 4; ++n) {
                        f16x4 pv;
#pragma unroll
                        for (int r = 0; r < 4; ++r) pv[r] = (f16)sf[mf][n][r];
                        *reinterpret_cast<f16x4*>(&Pl[w][mf * 16 + lr][n * 16 + lg * 4]) = pv;
                    }
                    if (norm) {
                        lsum[mf] = lsum[mf] * al + s;
#pragma unroll
                        for (int r = 0; r < 4; ++r) {
                            const float ar = __shfl(al, lg * 4 + r);
#pragma unroll
                            for (int n = 0; n < 4; ++n) zacc[mf][n][r] *= ar;
                        }
                    } else {
                        lsum[mf] += s;
                    }
                }
#pragma unroll
                for (int kt = 0; kt < 2; ++kt) {
                    f16x8 pa[2];
#pragma unroll
                    for (int mf = 0; mf < 2; ++mf)
                        pa[mf] = *reinterpret_cast<const f16x8*>(&Pl[w][mf * 16 + lr][kt * 32 + lg * 8]);
                    __builtin_amdgcn_s_setprio(1);
#pragma unroll
                    for (int n = 0; n < 4; ++n)
#pragma unroll
                        for (int mf = 0; mf < 2; ++mf)
                            zacc[mf][n] = __builtin_amdgcn_mfma_f32_16x16x32_f16(pa[mf], vf[kt][n], zacc[mf][n], 0, 0, 0);
                    __builtin_amdgcn_s_setprio(0);
                }
            }
            __builtin_amdgcn_s_barrier(); // buffer-reuse protection
        }
#pragma unroll
        for (int mf = 0; mf < 2; ++mf) {
            const float inv = 1.0f / lsum[mf];
#pragma unroll
            for (int r = 0; r < 4; ++r) {
                const float ir = __shfl(inv, lg * 4 + r);
#pragma unroll
                for (int n = 0; n < 4; ++n)
                    Z[base + (size_t)(wq0 + mf * 16 + lg * 4 + r) * D_ + n * 16 + lr] =
                        (f16)(zacc[mf][n][r] * ir);
            }
        }
    }
}

// ---------------------------------------------------------------- launcher
extern "C" void kernel_launch(void* const* d_in, const int* in_sizes, int n_in,
                              void* d_out, int out_size, void* d_ws, size_t ws_size,
                              hipStream_t stream) {
    const float* data    = (const float*)d_in[0];
    const float* context = (const float*)d_in[1];
    const float* Wq = (const float*)d_in[2];
    const float* bq = (const float*)d_in[3];
    const float* Wk = (const float*)d_in[4];
    const float* bk = (const float*)d_in[5];
    const float* Wv = (const float*)d_in[6];
    const float* bv = (const float*)d_in[7];
    const float* Wo = (const float*)d_in[8];
    const float* bo = (const float*)d_in[9];

    const size_t MD = (size_t)M_ * D_;
    const size_t DD = (size_t)D_ * D_;
    f16* dataB = (f16*)d_ws;
    f16* ctxB  = dataB + MD;
    f16* WqT   = ctxB + MD;   // WqT,WkT,WvT,WoT contiguous
    f16* WkT   = WqT + DD;
    f16* WvT   = WkT + DD;
    f16* WoT   = WvT + DD;
    f16* Qb    = WoT + DD;
    f16* Kb    = Qb + MD;
    f16* VtB   = Kb + MD;     // [B][H][HD][S]
    f16* Zb    = VtB + MD;

    const int n4 = (int)(MD / 4);
    cvt2_kernel<<<2 * n4 / 256, 256, 0, stream>>>(data, context, dataB, n4);
    transpose_cvt4_kernel<<<dim3(32, 32, 4), 256, 0, stream>>>(Wq, Wk, Wv, Wo, WqT);

    gemm_qkv<<<dim3(24, 64), 256, 0, stream>>>(dataB, ctxB, WqT, bq, bk, bv, Qb, Kb, VtB);

    attn_kernel<<<dim3(H_, B_, 8), 256, 0, stream>>>(Qb, Kb, VtB, Zb);

    gemm_out<<<dim3(8, 64), 256, 0, stream>>>(Zb, WoT, bo, (float*)d_out);
}

// Round 10
// 188.158 us; speedup vs baseline: 2.0745x; 1.0678x over previous
//
#include <hip/hip_runtime.h>

// Problem constants
#define B_  4
#define S_  2048
#define D_  1024
#define H_  16
#define HD_ 64
#define M_  (B_*S_)   // 8192 rows total

typedef _Float16 f16;
typedef f16  f16x8 __attribute__((ext_vector_type(8)));
typedef f16  f16x4 __attribute__((ext_vector_type(4)));
typedef float f32x4 __attribute__((ext_vector_type(4)));

// global -> LDS direct DMA, 16B per lane. LDS dest = wave-uniform base + lane*16.
__device__ __forceinline__ void gload_lds16(const f16* g, f16* l) {
    __builtin_amdgcn_global_load_lds(
        (const __attribute__((address_space(1))) void*)g,
        (__attribute__((address_space(3))) void*)l, 16, 0, 0);
}

// ---------------------------------------------------------------- converts (fused: data+context)
__global__ __launch_bounds__(256) void cvt2_kernel(const float* __restrict__ a,
                                                   const float* __restrict__ c,
                                                   f16* __restrict__ out, int n4each) {
    int i = blockIdx.x * 256 + threadIdx.x;
    const float* src = (i < n4each) ? a : c;
    int j = (i < n4each) ? i : i - n4each;
    f32x4 v = *reinterpret_cast<const f32x4*>(src + (size_t)j * 4);
    *reinterpret_cast<f16x4*>(out + (size_t)i * 4) = __builtin_convertvector(v, f16x4);
}

// all four weights W[K][N] f32 -> WT[N][K] f16 (outputs contiguous per z)
__global__ __launch_bounds__(256) void transpose_cvt4_kernel(const float* __restrict__ Wq,
                                                             const float* __restrict__ Wk,
                                                             const float* __restrict__ Wv,
                                                             const float* __restrict__ Wo,
                                                             f16* __restrict__ WT) {
    __shared__ float tile[32][33];
    const int z = blockIdx.z;
    const float* W = (z == 0) ? Wq : (z == 1) ? Wk : (z == 2) ? Wv : Wo;
    f16* dst = WT + (size_t)z * D_ * D_;
    const int n0 = blockIdx.x * 32, k0 = blockIdx.y * 32;
    const int tx = threadIdx.x & 31, ty = threadIdx.x >> 5; // (32,8)
#pragma unroll
    for (int j = 0; j < 4; ++j)
        tile[ty + 8 * j][tx] = W[(size_t)(k0 + ty + 8 * j) * D_ + n0 + tx];
    __syncthreads();
#pragma unroll
    for (int j = 0; j < 4; ++j)
        dst[(size_t)(n0 + ty + 8 * j) * D_ + k0 + tx] = (f16)tile[tx][ty + 8 * j];
}

// ---------------------------------------------------------------- fused QKV GEMM, 8-phase 256x256
// BM=BN=256, BK=64, 512 threads = 8 waves (2 M x 4 N), per-wave out 128x64.
// LDS 128KB dynamic: A/B x dbuf x 2 halves of [128 rows][64 f16], XOR-swizzled slots.
// Per K-tile: 4 phases {ds-read subtile; stage 1 half-tile(t+1); vmcnt(4); barrier;
// setprio+16 MFMA+setprio; barrier}. vmcnt never drains in main loop (T3+T4).
// XCD-chunked remap (384 blocks = 48/XCD). seg = wx>>2 (0=Q,1=K,2=V).
__global__ __launch_bounds__(512, 2) void gemm_qkv8(const f16* __restrict__ Adata,
                                                    const f16* __restrict__ Actx,
                                                    const f16* __restrict__ Wt,
                                                    const float* __restrict__ bq,
                                                    const float* __restrict__ bk,
                                                    const float* __restrict__ bv,
                                                    f16* __restrict__ Qb,
                                                    f16* __restrict__ Kb,
                                                    f16* __restrict__ VtB) {
    extern __shared__ __align__(16) f16 SM[]; // 131072 B: A[2][2][8192], B at +32768
    constexpr int K = D_;
    constexpr int NT = K / 64; // 16 K-tiles
    const int id = (int)(blockIdx.y * 12 + blockIdx.x); // 0..383
    const int work = (id & 7) * 48 + (id >> 3);         // bijective (384 % 8 == 0)
    const int wy = work / 12, wx = work - wy * 12;
    const int seg = wx >> 2;
    const f16* __restrict__ A = seg ? Actx : Adata;
    const int m0 = wy * 256, n0 = wx * 256;
    const int tid = (int)threadIdx.x;
    const int w = tid >> 6, l = tid & 63, lr = l & 15, lg = l >> 4;
    const int wr = w >> 2, wc = w & 3;
    const int swx = lr & 7;
    // staging: per half-tile 1024 chunks of 16B; thread covers chunks tid, tid+512.
    const int srow = tid >> 3;            // rows srow and srow+64 ((+64)&7 == &7)
    const int g16 = (tid & 7) ^ (srow & 7); // pre-swizzled global 16B-slot

    auto stageH = [&](int buf, int kt, int mat, int h) {
        const f16* __restrict__ src = mat ? (Wt + (size_t)(n0 + h * 128) * K)
                                          : (A + (size_t)(m0 + h * 128) * K);
        f16* dst = SM + mat * 32768 + buf * 16384 + h * 8192;
        const int kk0 = kt * 64;
        gload_lds16(src + (size_t)srow * K + kk0 + g16 * 8, dst + w * 512);
        gload_lds16(src + (size_t)(srow + 64) * K + kk0 + g16 * 8, dst + 4096 + w * 512);
    };
    auto LDA = [&](int buf, int m, int kk) -> f16x8 {
        const int gr = m * 32 + wr * 16 + lr; // 0..255; &7 == lr&7
        return *reinterpret_cast<const f16x8*>(
            SM + buf * 16384 + (gr >> 7) * 8192 + (gr & 127) * 64 + (((kk * 4 + lg) ^ swx) * 8));
    };
    auto LDB = [&](int buf, int n, int kk) -> f16x8 {
        const int gr = n * 64 + wc * 16 + lr;
        return *reinterpret_cast<const f16x8*>(
            SM + 32768 + buf * 16384 + (gr >> 7) * 8192 + (gr & 127) * 64 + (((kk * 4 + lg) ^ swx) * 8));
    };

    f32x4 acc[8][4] = {};
    // prologue: tile 0's four halves, in read order
    stageH(0, 0, 0, 0); stageH(0, 0, 1, 0); stageH(0, 0, 1, 1); stageH(0, 0, 0, 1);
    asm volatile("s_waitcnt vmcnt(4)" ::: "memory"); // A-h0, B-h0 landed
    __builtin_amdgcn_s_barrier();

    for (int t = 0; t < NT; ++t) {
        const int buf = t & 1, nb = buf ^ 1;
        const bool nl = (t + 1 < NT);
        f16x8 a[4][2], b[4][2];
        // ---- P1: reads m0..3 (A-h0) + n0..1 (B-h0); stage A-h0(t+1)
#pragma unroll
        for (int m = 0; m < 4; ++m) { a[m][0] = LDA(buf, m, 0); a[m][1] = LDA(buf, m, 1); }
#pragma unroll
        for (int n = 0; n < 2; ++n) { b[n][0] = LDB(buf, n, 0); b[n][1] = LDB(buf, n, 1); }
        if (nl) { stageH(nb, t + 1, 0, 0); asm volatile("s_waitcnt vmcnt(4)" ::: "memory"); }
        else    { asm volatile("s_waitcnt vmcnt(2)" ::: "memory"); } // B-h1(t) ready
        __builtin_amdgcn_s_barrier();
        __builtin_amdgcn_s_setprio(1);
#pragma unroll
        for (int kk = 0; kk < 2; ++kk)
#pragma unroll
            for (int m = 0; m < 4; ++m)
#pragma unroll
                for (int n = 0; n < 2; ++n)
                    acc[m][n] = __builtin_amdgcn_mfma_f32_16x16x32_f16(a[m][kk], b[n][kk], acc[m][n], 0, 0, 0);
        __builtin_amdgcn_s_setprio(0);
        __builtin_amdgcn_s_barrier();
        // ---- P2: reads n2..3 (B-h1); stage B-h0(t+1)
#pragma unroll
        for (int n = 2; n < 4; ++n) { b[n][0] = LDB(buf, n, 0); b[n][1] = LDB(buf, n, 1); }
        if (nl) { stageH(nb, t + 1, 1, 0); asm volatile("s_waitcnt vmcnt(4)" ::: "memory"); }
        else    { asm volatile("s_waitcnt vmcnt(0)" ::: "memory"); } // A-h1(t) ready
        __builtin_amdgcn_s_barrier();
        __builtin_amdgcn_s_setprio(1);
#pragma unroll
        for (int kk = 0; kk < 2; ++kk)
#pragma unroll
            for (int m = 0; m < 4; ++m)
#pragma unroll
                for (int n = 2; n < 4; ++n)
                    acc[m][n] = __builtin_amdgcn_mfma_f32_16x16x32_f16(a[m][kk], b[n][kk], acc[m][n], 0, 0, 0);
        __builtin_amdgcn_s_setprio(0);
        __builtin_amdgcn_s_barrier();
        // ---- P3: reads m4..7 (A-h1, reuse a regs); stage B-h1(t+1)
#pragma unroll
        for (int m = 0; m < 4; ++m) { a[m][0] = LDA(buf, m + 4, 0); a[m][1] = LDA(buf, m + 4, 1); }
        if (nl) stageH(nb, t + 1, 1, 1);
        __builtin_amdgcn_s_barrier();
        __builtin_amdgcn_s_setprio(1);
#pragma unroll
        for (int kk = 0; kk < 2; ++kk)
#pragma unroll
            for (int m = 0; m < 4; ++m)
#pragma unroll
                for (int n = 2; n < 4; ++n)
                    acc[m + 4][n] = __builtin_amdgcn_mfma_f32_16x16x32_f16(a[m][kk], b[n][kk], acc[m + 4][n], 0, 0, 0);
        __builtin_amdgcn_s_setprio(0);
        __builtin_amdgcn_s_barrier();
        // ---- P4: no reads; stage A-h1(t+1); vmcnt guards next tile's A-h0/B-h0
        if (nl) { stageH(nb, t + 1, 0, 1); asm volatile("s_waitcnt vmcnt(4)" ::: "memory"); }
        __builtin_amdgcn_s_barrier();
        __builtin_amdgcn_s_setprio(1);
#pragma unroll
        for (int kk = 0; kk < 2; ++kk)
#pragma unroll
            for (int m = 0; m < 4; ++m)
#pragma unroll
                for (int n = 0; n < 2; ++n)
                    acc[m + 4][n] = __builtin_amdgcn_mfma_f32_16x16x32_f16(a[m][kk], b[n][kk], acc[m + 4][n], 0, 0, 0);
        __builtin_amdgcn_s_setprio(0);
        __builtin_amdgcn_s_barrier();
    }
    // ---- epilogue
    const float* bias = (seg == 0) ? bq : (seg == 1) ? bk : bv;
#pragma unroll
    for (int n = 0; n < 4; ++n) {
        const int col = n0 + n * 64 + wc * 16 + lr;
        const int lc = col & 1023;
        const float bvv = bias[lc];
#pragma unroll
        for (int m = 0; m < 8; ++m) {
            const int row = m0 + m * 32 + wr * 16 + lg * 4;
            if (seg == 2) { // V: transposed VT[B][H*HD][S], rows->s contiguous
                const int bb = row >> 11, s0 = row & 2047;
                f16x4 v;
#pragma unroll
                for (int r = 0; r < 4; ++r) v[r] = (f16)(acc[m][n][r] + bvv);
                *reinterpret_cast<f16x4*>(VtB + ((size_t)(bb * D_ + lc)) * S_ + s0) = v;
            } else {
                f16* dst = seg ? Kb : Qb;
#pragma unroll
                for (int r = 0; r < 4; ++r)
                    dst[(size_t)(row + r) * D_ + lc] = (f16)(acc[m][n][r] + bvv);
            }
        }
    }
}

// ---------------------------------------------------------------- output GEMM  C = A @ Bt^T + bias (f32 out)
// 2-phase 128^2, XCD-chunked remap (512 blocks, 64/XCD).
__global__ __launch_bounds__(256) void gemm_out(const f16* __restrict__ A,
                                                const f16* __restrict__ Bt,
                                                const float* __restrict__ bias,
                                                float* __restrict__ C) {
    constexpr int K = D_;
    constexpr int NT = K / 32;
    __shared__ __align__(16) f16 Al[2][128 * 32];
    __shared__ __align__(16) f16 Bl[2][128 * 32];
    const int id = (int)(blockIdx.y * 8 + blockIdx.x);
    const int work = (id & 7) * 64 + (id >> 3);
    const int wy = work >> 3, wx = work & 7;
    const int m0 = wy * 128, n0 = wx * 128;
    const int tid = threadIdx.x;
    const int w = tid >> 6, l = tid & 63, lr = l & 15, lg = l >> 4;
    const int wr = w >> 1, wc = w & 1;
    const int srow = tid >> 2, soff = (tid & 3) * 8;

    auto stage = [&](int buf, int kk) {
#pragma unroll
        for (int i = 0; i < 2; ++i) {
            const int row = srow + i * 64;
            gload_lds16(A  + (size_t)(m0 + row) * K + kk + soff, &Al[buf][(w + 4 * i) * 512]);
            gload_lds16(Bt + (size_t)(n0 + row) * K + kk + soff, &Bl[buf][(w + 4 * i) * 512]);
        }
    };

    f32x4 acc[4][4] = {};
    stage(0, 0);
    for (int t = 0; t < NT; ++t) {
        const int buf = t & 1;
        if (t + 1 < NT) {
            stage(buf ^ 1, (t + 1) * 32);
            asm volatile("s_waitcnt vmcnt(4)" ::: "memory");
        } else {
            asm volatile("s_waitcnt vmcnt(0)" ::: "memory");
        }
        __builtin_amdgcn_s_barrier();
        f16x8 a[4], b[4];
#pragma unroll
        for (int m = 0; m < 4; ++m)
            a[m] = *reinterpret_cast<const f16x8*>(&Al[buf][(wr * 64 + m * 16 + lr) * 32 + lg * 8]);
#pragma unroll
        for (int n = 0; n < 4; ++n)
            b[n] = *reinterpret_cast<const f16x8*>(&Bl[buf][(wc * 64 + n * 16 + lr) * 32 + lg * 8]);
        __builtin_amdgcn_s_setprio(1);
#pragma unroll
        for (int m = 0; m < 4; ++m)
#pragma unroll
            for (int n = 0; n < 4; ++n)
                acc[m][n] = __builtin_amdgcn_mfma_f32_16x16x32_f16(a[m], b[n], acc[m][n], 0, 0, 0);
        __builtin_amdgcn_s_setprio(0);
        __builtin_amdgcn_s_barrier();
    }
#pragma unroll
    for (int n = 0; n < 4; ++n) {
        const int col = n0 + wc * 64 + n * 16 + lr;
        const float bv = bias[col];
#pragma unroll
        for (int m = 0; m < 4; ++m) {
            const int row = m0 + wr * 64 + m * 16 + lg * 4;
#pragma unroll
            for (int r = 0; r < 4; ++r)
                C[(size_t)(row + r) * D_ + col] = acc[m][n][r] + bv;
        }
    }
}

// ---------------------------------------------------------------- causal flash attention
// grid (H, B, 8), 256 threads = 4 waves. Block handles q-tiles {15-pp, pp}.
// K,V staged to LDS via global_load_lds, double-buffered, XOR-swizzled both sides.
// Counted vmcnt(4). Swapped QK^T; scale fused into exp FMA; defer-max; P via LDS.
__global__ __launch_bounds__(256, 2) void attn_kernel(const f16* __restrict__ Q,
                                                      const f16* __restrict__ Kg,
                                                      const f16* __restrict__ Vt,
                                                      f16* __restrict__ Z) {
    __shared__ __align__(16) f16 KL[2][64 * 64];
    __shared__ __align__(16) f16 VL[2][64 * 64];
    __shared__ __align__(16) f16 Pl[4][32][72];
    const int h = blockIdx.x, b = blockIdx.y, pp = blockIdx.z;
    const int tid = threadIdx.x, w = tid >> 6, l = tid & 63, lr = l & 15, lg = l >> 4;
    const size_t base   = ((size_t)b * S_) * D_ + h * HD_;
    const size_t vtbase = ((size_t)(b * D_ + h * HD_)) * S_;
    const f16* __restrict__ Kbase = Kg + base;
    const f16* __restrict__ Vbase = Vt + vtbase;
    const float sc = 0.125f * 1.44269504f; // 1/sqrt(64) * log2(e)
    const int sw_xor = lr & 7;

    auto stageKV = [&](int buf, int t0) {
#pragma unroll
        for (int i = 0; i < 2; ++i) {
            const int c = i * 256 + tid;
            const int row = c >> 3, g16 = (c & 7) ^ (row & 7);
            f16* dstK = &KL[buf][(i * 256 + w * 64) * 8];
            f16* dstV = &VL[buf][(i * 256 + w * 64) * 8];
            gload_lds16(Kbase + (size_t)(t0 + row) * D_ + g16 * 8, dstK);
            gload_lds16(Vbase + (size_t)row * S_ + t0 + g16 * 8, dstV);
        }
    };

    for (int half = 0; half < 2; ++half) {
        const int qt = half ? pp : (15 - pp);
        const int q0 = qt * 128, wq0 = q0 + w * 32;
        const int ntw = ((wq0 + 31) >> 6) + 1;
        const int ntb = qt * 2 + 2;

        f16x8 qf[2][2];
#pragma unroll
        for (int mf = 0; mf < 2; ++mf)
#pragma unroll
            for (int kd = 0; kd < 2; ++kd)
                qf[mf][kd] = *reinterpret_cast<const f16x8*>(
                    Q + base + (size_t)(wq0 + mf * 16 + lr) * D_ + kd * 32 + lg * 8);

        f32x4 zacc[2][4] = {};
        float mrun[2] = {-3.0e38f, -3.0e38f}, lsum[2] = {0.f, 0.f};

        stageKV(0, 0);
        for (int t = 0; t < ntb; ++t) {
            const int buf = t & 1;
            if (t + 1 < ntb) {
                stageKV(buf ^ 1, (t + 1) * 64);
                asm volatile("s_waitcnt vmcnt(4)" ::: "memory");
            } else {
                asm volatile("s_waitcnt vmcnt(0)" ::: "memory");
            }
            __builtin_amdgcn_s_barrier();
            if (t < ntw) {
                const int t0 = t * 64;
                f16x8 kf[2][4];
#pragma unroll
                for (int kd = 0; kd < 2; ++kd)
#pragma unroll
                    for (int n = 0; n < 4; ++n)
                        kf[kd][n] = *reinterpret_cast<const f16x8*>(
                            &KL[buf][(n * 16 + lr) * 64 + (((kd * 4 + lg) ^ sw_xor) * 8)]);
                f32x4 sf[2][4] = {};
                __builtin_amdgcn_s_setprio(1);
#pragma unroll
                for (int kd = 0; kd < 2; ++kd)
#pragma unroll
                    for (int n = 0; n < 4; ++n)
#pragma unroll
                        for (int mf = 0; mf < 2; ++mf)
                            sf[mf][n] = __builtin_amdgcn_mfma_f32_16x16x32_f16(kf[kd][n], qf[mf][kd], sf[mf][n], 0, 0, 0);
                __builtin_amdgcn_s_setprio(0);
                f16x8 vf[2][4];
#pragma unroll
                for (int kt = 0; kt < 2; ++kt)
#pragma unroll
                    for (int n = 0; n < 4; ++n)
                        vf[kt][n] = *reinterpret_cast<const f16x8*>(
                            &VL[buf][(n * 16 + lr) * 64 + (((kt * 4 + lg) ^ sw_xor) * 8)]);
                if (t == ntw - 1) {
#pragma unroll
                    for (int mf = 0; mf < 2; ++mf)
#pragma unroll
                        for (int n = 0; n < 4; ++n)
#pragma unroll
                            for (int r = 0; r < 4; ++r)
                                if ((t0 + n * 16 + lg * 4 + r) > (wq0 + mf * 16 + lr))
                                    sf[mf][n][r] = -3.0e38f;
                }
#pragma unroll
                for (int mf = 0; mf < 2; ++mf) {
                    f32x4 t4;
#pragma unroll
                    for (int r = 0; r < 4; ++r)
                        t4[r] = fmaxf(fmaxf(sf[mf][0][r], sf[mf][1][r]), fmaxf(sf[mf][2][r], sf[mf][3][r]));
                    float vmax = fmaxf(fmaxf(t4[0], t4[1]), fmaxf(t4[2], t4[3]));
                    vmax = fmaxf(vmax, __shfl_xor(vmax, 16));
                    vmax = fmaxf(vmax, __shfl_xor(vmax, 32));
                    const float vs = vmax * sc;
                    const bool norm = !__all(vs <= mrun[mf] + 10.0f);
                    float al = 1.0f;
                    if (norm) {
                        const float mnew = fmaxf(mrun[mf], vs);
                        al = __builtin_amdgcn_exp2f(mrun[mf] - mnew);
                        mrun[mf] = mnew;
                    }
                    float s = 0.f;
#pragma unroll
                    for (int n = 0; n < 4; ++n) {
                        f32x4 p;
#pragma unroll
                        for (int r = 0; r < 4; ++r)
                            p[r] = __builtin_amdgcn_exp2f(fmaf(sf[mf][n][r], sc, -mrun[mf]));
                        sf[mf][n] = p;
                        s += (p[0] + p[1]) + (p[2] + p[3]);
                    }
                    s += __shfl_xor(s, 16);
                    s += __shfl_xor(s, 32);
#pragma unroll
                    for (int n = 0; n < 4; ++n) {
                        f16x4 pv;
#pragma unroll
                        for (int r = 0; r < 4; ++r) pv[r] = (f16)sf[mf][n][r];
                        *reinterpret_cast<f16x4*>(&Pl[w][mf * 16 + lr][n * 16 + lg * 4]) = pv;
                    }
                    if (norm) {
                        lsum[mf] = lsum[mf] * al + s;
#pragma unroll
                        for (int r = 0; r < 4; ++r) {
                            const float ar = __shfl(al, lg * 4 + r);
#pragma unroll
                            for (int n = 0; n < 4; ++n) zacc[mf][n][r] *= ar;
                        }
                    } else {
                        lsum[mf] += s;
                    }
                }
#pragma unroll
                for (int kt = 0; kt < 2; ++kt) {
                    f16x8 pa[2];
#pragma unroll
                    for (int mf = 0; mf < 2; ++mf)
                        pa[mf] = *reinterpret_cast<const f16x8*>(&Pl[w][mf * 16 + lr][kt * 32 + lg * 8]);
                    __builtin_amdgcn_s_setprio(1);
#pragma unroll
                    for (int n = 0; n < 4; ++n)
#pragma unroll
                        for (int mf = 0; mf < 2; ++mf)
                            zacc[mf][n] = __builtin_amdgcn_mfma_f32_16x16x32_f16(pa[mf], vf[kt][n], zacc[mf][n], 0, 0, 0);
                    __builtin_amdgcn_s_setprio(0);
                }
            }
            __builtin_amdgcn_s_barrier();
        }
#pragma unroll
        for (int mf = 0; mf < 2; ++mf) {
            const float inv = 1.0f / lsum[mf];
#pragma unroll
            for (int r = 0; r < 4; ++r) {
                const float ir = __shfl(inv, lg * 4 + r);
#pragma unroll
                for (int n = 0; n < 4; ++n)
                    Z[base + (size_t)(wq0 + mf * 16 + lg * 4 + r) * D_ + n * 16 + lr] =
                        (f16)(zacc[mf][n][r] * ir);
            }
        }
    }
}

// ---------------------------------------------------------------- launcher
extern "C" void kernel_launch(void* const* d_in, const int* in_sizes, int n_in,
                              void* d_out, int out_size, void* d_ws, size_t ws_size,
                              hipStream_t stream) {
    const float* data    = (const float*)d_in[0];
    const float* context = (const float*)d_in[1];
    const float* Wq = (const float*)d_in[2];
    const float* bq = (const float*)d_in[3];
    const float* Wk = (const float*)d_in[4];
    const float* bk = (const float*)d_in[5];
    const float* Wv = (const float*)d_in[6];
    const float* bv = (const float*)d_in[7];
    const float* Wo = (const float*)d_in[8];
    const float* bo = (const float*)d_in[9];

    const size_t MD = (size_t)M_ * D_;
    const size_t DD = (size_t)D_ * D_;
    f16* dataB = (f16*)d_ws;
    f16* ctxB  = dataB + MD;
    f16* WqT   = ctxB + MD;   // WqT,WkT,WvT,WoT contiguous
    f16* WkT   = WqT + DD;
    f16* WvT   = WkT + DD;
    f16* WoT   = WvT + DD;
    f16* Qb    = WoT + DD;
    f16* Kb    = Qb + MD;
    f16* VtB   = Kb + MD;     // [B][H][HD][S]
    f16* Zb    = VtB + MD;

    (void)WkT; (void)WvT;

    const int n4 = (int)(MD / 4);
    cvt2_kernel<<<2 * n4 / 256, 256, 0, stream>>>(data, context, dataB, n4);
    transpose_cvt4_kernel<<<dim3(32, 32, 4), 256, 0, stream>>>(Wq, Wk, Wv, Wo, WqT);

    static bool attr_set = false;
    if (!attr_set) {
        hipFuncSetAttribute(reinterpret_cast<const void*>(gemm_qkv8),
                            hipFuncAttributeMaxDynamicSharedMemorySize, 131072);
        attr_set = true;
    }
    gemm_qkv8<<<dim3(12, 32), 512, 131072, stream>>>(dataB, ctxB, WqT, bq, bk, bv, Qb, Kb, VtB);

    attn_kernel<<<dim3(H_, B_, 8), 256, 0, stream>>>(Qb, Kb, VtB, Zb);

    gemm_out<<<dim3(8, 64), 256, 0, stream>>>(Zb, WoT, bo, (float*)d_out);
}

// Round 11
// 178.411 us; speedup vs baseline: 2.1879x; 1.0546x over previous
//
#include <hip/hip_runtime.h>

// Problem constants
#define B_  4
#define S_  2048
#define D_  1024
#define H_  16
#define HD_ 64
#define M_  (B_*S_)   // 8192 rows total

typedef _Float16 f16;
typedef f16  f16x8 __attribute__((ext_vector_type(8)));
typedef f16  f16x4 __attribute__((ext_vector_type(4)));
typedef float f32x4 __attribute__((ext_vector_type(4)));

// global -> LDS direct DMA, 16B per lane. LDS dest = wave-uniform base + lane*16.
__device__ __forceinline__ void gload_lds16(const f16* g, f16* l) {
    __builtin_amdgcn_global_load_lds(
        (const __attribute__((address_space(1))) void*)g,
        (__attribute__((address_space(3))) void*)l, 16, 0, 0);
}

// ---------------------------------------------------------------- converts (fused: data+context)
__global__ __launch_bounds__(256) void cvt2_kernel(const float* __restrict__ a,
                                                   const float* __restrict__ c,
                                                   f16* __restrict__ out, int n4each) {
    int i = blockIdx.x * 256 + threadIdx.x;
    const float* src = (i < n4each) ? a : c;
    int j = (i < n4each) ? i : i - n4each;
    f32x4 v = *reinterpret_cast<const f32x4*>(src + (size_t)j * 4);
    *reinterpret_cast<f16x4*>(out + (size_t)i * 4) = __builtin_convertvector(v, f16x4);
}

// all four weights W[K][N] f32 -> WT[N][K] f16 (outputs contiguous per z)
__global__ __launch_bounds__(256) void transpose_cvt4_kernel(const float* __restrict__ Wq,
                                                             const float* __restrict__ Wk,
                                                             const float* __restrict__ Wv,
                                                             const float* __restrict__ Wo,
                                                             f16* __restrict__ WT) {
    __shared__ float tile[32][33];
    const int z = blockIdx.z;
    const float* W = (z == 0) ? Wq : (z == 1) ? Wk : (z == 2) ? Wv : Wo;
    f16* dst = WT + (size_t)z * D_ * D_;
    const int n0 = blockIdx.x * 32, k0 = blockIdx.y * 32;
    const int tx = threadIdx.x & 31, ty = threadIdx.x >> 5; // (32,8)
#pragma unroll
    for (int j = 0; j < 4; ++j)
        tile[ty + 8 * j][tx] = W[(size_t)(k0 + ty + 8 * j) * D_ + n0 + tx];
    __syncthreads();
#pragma unroll
    for (int j = 0; j < 4; ++j)
        dst[(size_t)(n0 + ty + 8 * j) * D_ + k0 + tx] = (f16)tile[tx][ty + 8 * j];
}

// ---------------------------------------------------------------- 8-phase-style GEMM, BM=128 x BN=256, BK=64
// 512 threads = 8 waves (4M x 2N); per-wave 32x128 out (2 m-frags x 8 n-frags).
// LDS 96KB dyn: A[2buf][128][64] + B[2buf][2half][128][64], XOR-swizzled 16B slots.
// Per K-tile: 2 phases {ds_reads ; stage next-tile units ; counted vmcnt ; barrier ;
// setprio + 16 MFMA + setprio ; barrier}. vmcnt(2) once/tile, never drains mid-loop.
// MODE 0: fused QKV (768 blocks = 3 uniform rounds; seg=wx>>2: Q/K row-major, V transposed)
// MODE 1: output GEMM f32 (256 blocks = 1 uniform round; bias in bq slot)
template <int MODE>
__global__ __launch_bounds__(512) void gemm8(const f16* __restrict__ Adata,
                                             const f16* __restrict__ Actx,
                                             const f16* __restrict__ Wt,
                                             const float* __restrict__ bq,
                                             const float* __restrict__ bk,
                                             const float* __restrict__ bv,
                                             f16* __restrict__ Qb,
                                             f16* __restrict__ Kb,
                                             f16* __restrict__ VtB,
                                             float* __restrict__ Cout) {
    extern __shared__ __align__(16) f16 SM[]; // A: [0,16384), B: [16384,49152) f16 units
    constexpr int K = D_;
    constexpr int NT = K / 64;                  // 16 K-tiles
    constexpr int NXT = (MODE == 0) ? 12 : 4;   // N tiles of 256
    constexpr int PER = (MODE == 0) ? 96 : 32;  // works per XCD (bijective: blocks % 8 == 0)
    const int id = (int)blockIdx.x;
    const int work = (id & 7) * PER + (id >> 3);
    const int wy = work / NXT, wx = work - wy * NXT;
    const int seg = (MODE == 0) ? (wx >> 2) : 0;
    const f16* __restrict__ A = (MODE == 0) ? (seg ? Actx : Adata) : Adata;
    const int m0 = wy * 128, n0 = wx * 256;
    const int tid = (int)threadIdx.x;
    const int w = tid >> 6, lr = tid & 15, lg = (tid & 63) >> 4;
    const int wr = w >> 1, wc = w & 1;  // 4M x 2N
    const int swx = lr & 7;
    const int srow = tid >> 3;                 // staging rows srow, srow+64
    const int g16 = (tid & 7) ^ (srow & 7);    // pre-swizzled global 16B slot

    auto stageA = [&](int kt, int buf) {
        const f16* src = A + (size_t)(m0 + srow) * K + kt * 64 + g16 * 8;
        f16* dst = SM + buf * 8192;
        gload_lds16(src, dst + w * 512);
        gload_lds16(src + (size_t)64 * K, dst + 4096 + w * 512);
    };
    auto stageB = [&](int kt, int buf, int h) {
        const f16* src = Wt + (size_t)(n0 + h * 128 + srow) * K + kt * 64 + g16 * 8;
        f16* dst = SM + 16384 + buf * 16384 + h * 8192;
        gload_lds16(src, dst + w * 512);
        gload_lds16(src + (size_t)64 * K, dst + 4096 + w * 512);
    };
    auto LDA = [&](int buf, int m, int kk) -> f16x8 {
        return *reinterpret_cast<const f16x8*>(
            SM + buf * 8192 + (wr * 32 + m * 16 + lr) * 64 + (((kk * 4 + lg) ^ swx) * 8));
    };
    auto LDB = [&](int buf, int n, int kk) -> f16x8 {
        return *reinterpret_cast<const f16x8*>(
            SM + 16384 + buf * 16384 + wc * 8192 + (n * 16 + lr) * 64 + (((kk * 4 + lg) ^ swx) * 8));
    };

    f32x4 acc[2][8] = {};
    // prologue: tile0 (A,B0,B1) + A(1); verify tile0, leave A(1) in flight
    stageA(0, 0); stageB(0, 0, 0); stageB(0, 0, 1); stageA(1, 1);
    asm volatile("s_waitcnt vmcnt(2)" ::: "memory");
    __builtin_amdgcn_s_barrier();

    for (int t = 0; t < NT; ++t) {
        const int buf = t & 1, nb = buf ^ 1;
        f16x8 a[2][2], b[2][2];
        // ---- P1: reads a + b(n0..3 lower kk pairs), stage B(t+1)
#pragma unroll
        for (int m = 0; m < 2; ++m) { a[m][0] = LDA(buf, m, 0); a[m][1] = LDA(buf, m, 1); }
        b[0][0] = LDB(buf, 0, 0); b[0][1] = LDB(buf, 0, 1);
        b[1][0] = LDB(buf, 1, 0); b[1][1] = LDB(buf, 1, 1);
        f16x8 b2[2][2];
        b2[0][0] = LDB(buf, 2, 0); b2[0][1] = LDB(buf, 2, 1);
        b2[1][0] = LDB(buf, 3, 0); b2[1][1] = LDB(buf, 3, 1);
        if (t + 1 < NT) { stageB(t + 1, nb, 0); stageB(t + 1, nb, 1); }
        else { asm volatile("s_waitcnt vmcnt(0)" ::: "memory"); }
        __builtin_amdgcn_s_barrier();
        __builtin_amdgcn_s_setprio(1);
#pragma unroll
        for (int kk = 0; kk < 2; ++kk)
#pragma unroll
            for (int m = 0; m < 2; ++m) {
                acc[m][0] = __builtin_amdgcn_mfma_f32_16x16x32_f16(a[m][kk], b[0][kk], acc[m][0], 0, 0, 0);
                acc[m][1] = __builtin_amdgcn_mfma_f32_16x16x32_f16(a[m][kk], b[1][kk], acc[m][1], 0, 0, 0);
                acc[m][2] = __builtin_amdgcn_mfma_f32_16x16x32_f16(a[m][kk], b2[0][kk], acc[m][2], 0, 0, 0);
                acc[m][3] = __builtin_amdgcn_mfma_f32_16x16x32_f16(a[m][kk], b2[1][kk], acc[m][3], 0, 0, 0);
            }
        __builtin_amdgcn_s_setprio(0);
        __builtin_amdgcn_s_barrier();
        // ---- P2: reads b(n4..7), stage A(t+2), counted vmcnt once per tile
        b[0][0] = LDB(buf, 4, 0); b[0][1] = LDB(buf, 4, 1);
        b[1][0] = LDB(buf, 5, 0); b[1][1] = LDB(buf, 5, 1);
        b2[0][0] = LDB(buf, 6, 0); b2[0][1] = LDB(buf, 6, 1);
        b2[1][0] = LDB(buf, 7, 0); b2[1][1] = LDB(buf, 7, 1);
        if (t + 2 < NT) stageA(t + 2, buf);
        if (t + 1 < NT) { asm volatile("s_waitcnt vmcnt(2)" ::: "memory"); }
        __builtin_amdgcn_s_barrier();
        __builtin_amdgcn_s_setprio(1);
#pragma unroll
        for (int kk = 0; kk < 2; ++kk)
#pragma unroll
            for (int m = 0; m < 2; ++m) {
                acc[m][4] = __builtin_amdgcn_mfma_f32_16x16x32_f16(a[m][kk], b[0][kk], acc[m][4], 0, 0, 0);
                acc[m][5] = __builtin_amdgcn_mfma_f32_16x16x32_f16(a[m][kk], b[1][kk], acc[m][5], 0, 0, 0);
                acc[m][6] = __builtin_amdgcn_mfma_f32_16x16x32_f16(a[m][kk], b2[0][kk], acc[m][6], 0, 0, 0);
                acc[m][7] = __builtin_amdgcn_mfma_f32_16x16x32_f16(a[m][kk], b2[1][kk], acc[m][7], 0, 0, 0);
            }
        __builtin_amdgcn_s_setprio(0);
        __builtin_amdgcn_s_barrier();
    }
    // ---- epilogue
    if (MODE == 1) {
        const float* bias = bq; // bo passed here
#pragma unroll
        for (int n = 0; n < 8; ++n) {
            const int col = n0 + wc * 128 + n * 16 + lr;
            const float bvv = bias[col];
#pragma unroll
            for (int m = 0; m < 2; ++m) {
                const int row = m0 + wr * 32 + m * 16 + lg * 4;
#pragma unroll
                for (int r = 0; r < 4; ++r)
                    Cout[(size_t)(row + r) * D_ + col] = acc[m][n][r] + bvv;
            }
        }
    } else {
        const float* bias = (seg == 0) ? bq : (seg == 1) ? bk : bv;
#pragma unroll
        for (int n = 0; n < 8; ++n) {
            const int col = n0 + wc * 128 + n * 16 + lr;
            const int lc = col & 1023;
            const float bvv = bias[lc];
#pragma unroll
            for (int m = 0; m < 2; ++m) {
                const int row = m0 + wr * 32 + m * 16 + lg * 4;
                if (seg == 2) { // V transposed: VT[B][H*HD][S]
                    const int bb = row >> 11, s0 = row & 2047;
                    f16x4 v;
#pragma unroll
                    for (int r = 0; r < 4; ++r) v[r] = (f16)(acc[m][n][r] + bvv);
                    *reinterpret_cast<f16x4*>(VtB + ((size_t)(bb * D_ + lc)) * S_ + s0) = v;
                } else {
                    f16* dst = seg ? Kb : Qb;
#pragma unroll
                    for (int r = 0; r < 4; ++r)
                        dst[(size_t)(row + r) * D_ + lc] = (f16)(acc[m][n][r] + bvv);
                }
            }
        }
    }
}

// ---------------------------------------------------------------- causal flash attention
// grid (H, B, 8), 256 threads = 4 waves. Block handles q-tiles {15-pp, pp}.
// K,V staged to LDS via global_load_lds, double-buffered, XOR-swizzled both sides.
// Counted vmcnt(4). Swapped QK^T; scale fused into exp FMA; defer-max.
// lsum via ones-MFMA: row-sums accumulate in the zacc layout (no VALU sum, no shfls).
__global__ __launch_bounds__(256, 2) void attn_kernel(const f16* __restrict__ Q,
                                                      const f16* __restrict__ Kg,
                                                      const f16* __restrict__ Vt,
                                                      f16* __restrict__ Z) {
    __shared__ __align__(16) f16 KL[2][64 * 64];
    __shared__ __align__(16) f16 VL[2][64 * 64];
    __shared__ __align__(16) f16 Pl[4][32][72];
    const int h = blockIdx.x, b = blockIdx.y, pp = blockIdx.z;
    const int tid = threadIdx.x, w = tid >> 6, l = tid & 63, lr = l & 15, lg = l >> 4;
    const size_t base   = ((size_t)b * S_) * D_ + h * HD_;
    const size_t vtbase = ((size_t)(b * D_ + h * HD_)) * S_;
    const f16* __restrict__ Kbase = Kg + base;
    const f16* __restrict__ Vbase = Vt + vtbase;
    const float sc = 0.125f * 1.44269504f; // 1/sqrt(64) * log2(e)
    const int sw_xor = lr & 7;
    f16x8 onesv;
#pragma unroll
    for (int i = 0; i < 8; ++i) onesv[i] = (f16)1.0f;

    auto stageKV = [&](int buf, int t0) {
#pragma unroll
        for (int i = 0; i < 2; ++i) {
            const int c = i * 256 + tid;
            const int row = c >> 3, g16 = (c & 7) ^ (row & 7);
            f16* dstK = &KL[buf][(i * 256 + w * 64) * 8];
            f16* dstV = &VL[buf][(i * 256 + w * 64) * 8];
            gload_lds16(Kbase + (size_t)(t0 + row) * D_ + g16 * 8, dstK);
            gload_lds16(Vbase + (size_t)row * S_ + t0 + g16 * 8, dstV);
        }
    };

    for (int half = 0; half < 2; ++half) {
        const int qt = half ? pp : (15 - pp);
        const int q0 = qt * 128, wq0 = q0 + w * 32;
        const int ntw = ((wq0 + 31) >> 6) + 1;
        const int ntb = qt * 2 + 2;

        f16x8 qf[2][2];
#pragma unroll
        for (int mf = 0; mf < 2; ++mf)
#pragma unroll
            for (int kd = 0; kd < 2; ++kd)
                qf[mf][kd] = *reinterpret_cast<const f16x8*>(
                    Q + base + (size_t)(wq0 + mf * 16 + lr) * D_ + kd * 32 + lg * 8);

        f32x4 zacc[2][4] = {};
        f32x4 lsv[2] = {};                    // row-sums (zacc layout: row = lg*4+r)
        float mrun[2] = {-3.0e38f, -3.0e38f};

        stageKV(0, 0);
        for (int t = 0; t < ntb; ++t) {
            const int buf = t & 1;
            if (t + 1 < ntb) {
                stageKV(buf ^ 1, (t + 1) * 64);
                asm volatile("s_waitcnt vmcnt(4)" ::: "memory");
            } else {
                asm volatile("s_waitcnt vmcnt(0)" ::: "memory");
            }
            __builtin_amdgcn_s_barrier();
            if (t < ntw) {
                const int t0 = t * 64;
                f16x8 kf[2][4];
#pragma unroll
                for (int kd = 0; kd < 2; ++kd)
#pragma unroll
                    for (int n = 0; n < 4; ++n)
                        kf[kd][n] = *reinterpret_cast<const f16x8*>(
                            &KL[buf][(n * 16 + lr) * 64 + (((kd * 4 + lg) ^ sw_xor) * 8)]);
                f32x4 sf[2][4] = {};
                __builtin_amdgcn_s_setprio(1);
#pragma unroll
                for (int kd = 0; kd < 2; ++kd)
#pragma unroll
                    for (int n = 0; n < 4; ++n)
#pragma unroll
                        for (int mf = 0; mf < 2; ++mf)
                            sf[mf][n] = __builtin_amdgcn_mfma_f32_16x16x32_f16(kf[kd][n], qf[mf][kd], sf[mf][n], 0, 0, 0);
                __builtin_amdgcn_s_setprio(0);
                f16x8 vf[2][4];
#pragma unroll
                for (int kt = 0; kt < 2; ++kt)
#pragma unroll
                    for (int n = 0; n < 4; ++n)
                        vf[kt][n] = *reinterpret_cast<const f16x8*>(
                            &VL[buf][(n * 16 + lr) * 64 + (((kt * 4 + lg) ^ sw_xor) * 8)]);
                // mask only (raw scores); scale folds into the exp FMA below
                if (t == ntw - 1) {
#pragma unroll
                    for (int mf = 0; mf < 2; ++mf)
#pragma unroll
                        for (int n = 0; n < 4; ++n)
#pragma unroll
                            for (int r = 0; r < 4; ++r)
                                if ((t0 + n * 16 + lg * 4 + r) > (wq0 + mf * 16 + lr))
                                    sf[mf][n][r] = -3.0e38f;
                }
#pragma unroll
                for (int mf = 0; mf < 2; ++mf) {
                    f32x4 t4;
#pragma unroll
                    for (int r = 0; r < 4; ++r)
                        t4[r] = fmaxf(fmaxf(sf[mf][0][r], sf[mf][1][r]), fmaxf(sf[mf][2][r], sf[mf][3][r]));
                    float vmax = fmaxf(fmaxf(t4[0], t4[1]), fmaxf(t4[2], t4[3]));
                    vmax = fmaxf(vmax, __shfl_xor(vmax, 16));
                    vmax = fmaxf(vmax, __shfl_xor(vmax, 32));
                    const float vs = vmax * sc;
                    const bool norm = !__all(vs <= mrun[mf] + 10.0f);
                    if (norm) {
                        const float mnew = fmaxf(mrun[mf], vs);
                        const float al = __builtin_amdgcn_exp2f(mrun[mf] - mnew);
                        mrun[mf] = mnew;
#pragma unroll
                        for (int r = 0; r < 4; ++r) {
                            const float ar = __shfl(al, lg * 4 + r);
#pragma unroll
                            for (int n = 0; n < 4; ++n) zacc[mf][n][r] *= ar;
                            lsv[mf][r] *= ar;
                        }
                    }
#pragma unroll
                    for (int n = 0; n < 4; ++n) {
                        f32x4 p;
#pragma unroll
                        for (int r = 0; r < 4; ++r)
                            p[r] = __builtin_amdgcn_exp2f(fmaf(sf[mf][n][r], sc, -mrun[mf]));
                        f16x4 pv;
#pragma unroll
                        for (int r = 0; r < 4; ++r) pv[r] = (f16)p[r];
                        *reinterpret_cast<f16x4*>(&Pl[w][mf * 16 + lr][n * 16 + lg * 4]) = pv;
                    }
                }
#pragma unroll
                for (int kt = 0; kt < 2; ++kt) {
                    f16x8 pa[2];
#pragma unroll
                    for (int mf = 0; mf < 2; ++mf)
                        pa[mf] = *reinterpret_cast<const f16x8*>(&Pl[w][mf * 16 + lr][kt * 32 + lg * 8]);
                    __builtin_amdgcn_s_setprio(1);
#pragma unroll
                    for (int n = 0; n < 4; ++n)
#pragma unroll
                        for (int mf = 0; mf < 2; ++mf)
                            zacc[mf][n] = __builtin_amdgcn_mfma_f32_16x16x32_f16(pa[mf], vf[kt][n], zacc[mf][n], 0, 0, 0);
#pragma unroll
                    for (int mf = 0; mf < 2; ++mf)
                        lsv[mf] = __builtin_amdgcn_mfma_f32_16x16x32_f16(pa[mf], onesv, lsv[mf], 0, 0, 0);
                    __builtin_amdgcn_s_setprio(0);
                }
            }
            __builtin_amdgcn_s_barrier();
        }
#pragma unroll
        for (int mf = 0; mf < 2; ++mf) {
            f32x4 inv;
#pragma unroll
            for (int r = 0; r < 4; ++r) inv[r] = 1.0f / lsv[mf][r];
#pragma unroll
            for (int r = 0; r < 4; ++r)
#pragma unroll
                for (int n = 0; n < 4; ++n)
                    Z[base + (size_t)(wq0 + mf * 16 + lg * 4 + r) * D_ + n * 16 + lr] =
                        (f16)(zacc[mf][n][r] * inv[r]);
        }
    }
}

// ---------------------------------------------------------------- launcher
extern "C" void kernel_launch(void* const* d_in, const int* in_sizes, int n_in,
                              void* d_out, int out_size, void* d_ws, size_t ws_size,
                              hipStream_t stream) {
    const float* data    = (const float*)d_in[0];
    const float* context = (const float*)d_in[1];
    const float* Wq = (const float*)d_in[2];
    const float* bq = (const float*)d_in[3];
    const float* Wk = (const float*)d_in[4];
    const float* bk = (const float*)d_in[5];
    const float* Wv = (const float*)d_in[6];
    const float* bv = (const float*)d_in[7];
    const float* Wo = (const float*)d_in[8];
    const float* bo = (const float*)d_in[9];

    const size_t MD = (size_t)M_ * D_;
    const size_t DD = (size_t)D_ * D_;
    f16* dataB = (f16*)d_ws;
    f16* ctxB  = dataB + MD;
    f16* WqT   = ctxB + MD;   // WqT,WkT,WvT,WoT contiguous
    f16* WkT   = WqT + DD;
    f16* WvT   = WkT + DD;
    f16* WoT   = WvT + DD;
    f16* Qb    = WoT + DD;
    f16* Kb    = Qb + MD;
    f16* VtB   = Kb + MD;     // [B][H][HD][S]
    f16* Zb    = VtB + MD;

    (void)WkT; (void)WvT;

    const int n4 = (int)(MD / 4);
    cvt2_kernel<<<2 * n4 / 256, 256, 0, stream>>>(data, context, dataB, n4);
    transpose_cvt4_kernel<<<dim3(32, 32, 4), 256, 0, stream>>>(Wq, Wk, Wv, Wo, WqT);

    hipFuncSetAttribute(reinterpret_cast<const void*>(gemm8<0>),
                        hipFuncAttributeMaxDynamicSharedMemorySize, 98304);
    hipFuncSetAttribute(reinterpret_cast<const void*>(gemm8<1>),
                        hipFuncAttributeMaxDynamicSharedMemorySize, 98304);

    gemm8<0><<<768, 512, 98304, stream>>>(dataB, ctxB, WqT, bq, bk, bv,
                                          Qb, Kb, VtB, nullptr);

    attn_kernel<<<dim3(H_, B_, 8), 256, 0, stream>>>(Qb, Kb, VtB, Zb);

    gemm8<1><<<256, 512, 98304, stream>>>(Zb, nullptr, WoT, bo, nullptr, nullptr,
                                          nullptr, nullptr, nullptr, (float*)d_out);
}

// Round 12
// 170.794 us; speedup vs baseline: 2.2855x; 1.0446x over previous
//
#include <hip/hip_runtime.h>

// Problem constants
#define B_  4
#define S_  2048
#define D_  1024
#define H_  16
#define HD_ 64
#define M_  (B_*S_)   // 8192 rows total

typedef _Float16 f16;
typedef f16  f16x8 __attribute__((ext_vector_type(8)));
typedef f16  f16x4 __attribute__((ext_vector_type(4)));
typedef float f32x4 __attribute__((ext_vector_type(4)));

// global -> LDS direct DMA, 16B per lane. LDS dest = wave-uniform base + lane*16.
__device__ __forceinline__ void gload_lds16(const f16* g, f16* l) {
    __builtin_amdgcn_global_load_lds(
        (const __attribute__((address_space(1))) void*)g,
        (__attribute__((address_space(3))) void*)l, 16, 0, 0);
}

// ---------------------------------------------------------------- converts (fused: data+context)
__global__ __launch_bounds__(256) void cvt2_kernel(const float* __restrict__ a,
                                                   const float* __restrict__ c,
                                                   f16* __restrict__ out, int n4each) {
    int i = blockIdx.x * 256 + threadIdx.x;
    const float* src = (i < n4each) ? a : c;
    int j = (i < n4each) ? i : i - n4each;
    f32x4 v = *reinterpret_cast<const f32x4*>(src + (size_t)j * 4);
    *reinterpret_cast<f16x4*>(out + (size_t)i * 4) = __builtin_convertvector(v, f16x4);
}

// all four weights W[K][N] f32 -> WT[N][K] f16 (outputs contiguous per z)
__global__ __launch_bounds__(256) void transpose_cvt4_kernel(const float* __restrict__ Wq,
                                                             const float* __restrict__ Wk,
                                                             const float* __restrict__ Wv,
                                                             const float* __restrict__ Wo,
                                                             f16* __restrict__ WT) {
    __shared__ float tile[32][33];
    const int z = blockIdx.z;
    const float* W = (z == 0) ? Wq : (z == 1) ? Wk : (z == 2) ? Wv : Wo;
    f16* dst = WT + (size_t)z * D_ * D_;
    const int n0 = blockIdx.x * 32, k0 = blockIdx.y * 32;
    const int tx = threadIdx.x & 31, ty = threadIdx.x >> 5; // (32,8)
#pragma unroll
    for (int j = 0; j < 4; ++j)
        tile[ty + 8 * j][tx] = W[(size_t)(k0 + ty + 8 * j) * D_ + n0 + tx];
    __syncthreads();
#pragma unroll
    for (int j = 0; j < 4; ++j)
        dst[(size_t)(n0 + ty + 8 * j) * D_ + k0 + tx] = (f16)tile[tx][ty + 8 * j];
}

// ---------------------------------------------------------------- triple-buffered GEMM, BM=128 x BN=256, BK=32
// 256 threads = 4 waves (2M x 2N); per-wave 64x128 out (4m x 8n frags) -> 375 B
// LDS traffic per MFMA (HK-level reuse). LDS 72KB = 3 bufs x (A 8KB + B 16KB),
// XOR-swizzled 16B slots. Depth-2 staging: stage(t+2) each step, vmcnt(6) waits
// only tile t+1 (never drains mid-loop). One barrier per K-step.
// __launch_bounds__(256,2): 2 independent blocks/CU -> cross-block stall overlap.
// MODE 0: fused QKV, 768 blocks (seg = wx>>2: Q/K row-major, V transposed).
// MODE 1: output GEMM f32, 256 blocks (all co-resident).
template <int MODE>
__global__ __launch_bounds__(256, 2) void gemm3p(const f16* __restrict__ Adata,
                                                 const f16* __restrict__ Actx,
                                                 const f16* __restrict__ Wt,
                                                 const float* __restrict__ b0,
                                                 const float* __restrict__ b1,
                                                 const float* __restrict__ b2,
                                                 f16* __restrict__ Qb,
                                                 f16* __restrict__ Kb,
                                                 f16* __restrict__ VtB,
                                                 float* __restrict__ Cout) {
    extern __shared__ __align__(16) f16 SM[]; // 3 x 12288 f16 (A 4096 + B 8192 each)
    constexpr int K = D_;
    constexpr int NT = K / 32;                  // 32 K-steps
    constexpr int NXT = (MODE == 0) ? 12 : 4;   // N tiles of 256
    constexpr int PER = (MODE == 0) ? 96 : 32;  // works per XCD (blocks % 8 == 0)
    const int id = (int)blockIdx.x;
    const int work = (id & 7) * PER + (id >> 3); // XCD-chunked, bijective
    const int wy = work / NXT, wx = work - wy * NXT;
    const int seg = (MODE == 0) ? (wx >> 2) : 0;
    const f16* __restrict__ A = (MODE == 0) ? (seg ? Actx : Adata) : Adata;
    const int m0 = wy * 128, n0 = wx * 256;
    const int tid = (int)threadIdx.x;
    const int w = tid >> 6, lr = tid & 15, lg = (tid & 63) >> 4;
    const int wr = w >> 1, wc = w & 1;      // 2M x 2N
    const int sw = (lr >> 1) & 3;           // read-side slot XOR

    auto stage = [&](int buf, int kt) {
        const int kk0 = kt * 32;
        f16* base = SM + buf * 12288;
        // A: 128 rows x 32 f16 = 512 chunks of 16B, 2 per thread
#pragma unroll
        for (int j = 0; j < 2; ++j) {
            const int c = j * 256 + tid;
            const int row = c >> 2;
            const int ks = ((c & 3) ^ ((row >> 1) & 3)) * 8; // pre-swizzled k-slot
            gload_lds16(A + (size_t)(m0 + row) * K + kk0 + ks,
                        base + (j * 256 + w * 64) * 8);
        }
        // B: 256 rows x 32 f16 = 1024 chunks, 4 per thread
#pragma unroll
        for (int j = 0; j < 4; ++j) {
            const int c = j * 256 + tid;
            const int row = c >> 2;
            const int ks = ((c & 3) ^ ((row >> 1) & 3)) * 8;
            gload_lds16(Wt + (size_t)(n0 + row) * K + kk0 + ks,
                        base + 4096 + (j * 256 + w * 64) * 8);
        }
    };
    auto LDA = [&](int buf, int m) -> f16x8 {
        return *reinterpret_cast<const f16x8*>(
            SM + buf * 12288 + (wr * 64 + m * 16 + lr) * 32 + ((lg ^ sw) * 8));
    };
    auto LDB = [&](int buf, int n) -> f16x8 {
        return *reinterpret_cast<const f16x8*>(
            SM + buf * 12288 + 4096 + (wc * 128 + n * 16 + lr) * 32 + ((lg ^ sw) * 8));
    };

    f32x4 acc[4][8] = {};
    // prologue: tiles 0,1 staged; verify tile 0 (6 newest = tile 1 stay in flight)
    stage(0, 0);
    stage(1, 1);
    asm volatile("s_waitcnt vmcnt(6)" ::: "memory");
    __builtin_amdgcn_s_barrier();

    int buf = 0;
    for (int t = 0; t < NT; ++t) {
        if (t + 2 < NT) {
            int nb = buf + 2; if (nb >= 3) nb -= 3;
            stage(nb, t + 2);
        }
        f16x8 a[4], b[8];
#pragma unroll
        for (int m = 0; m < 4; ++m) a[m] = LDA(buf, m);
#pragma unroll
        for (int n = 0; n < 8; ++n) b[n] = LDB(buf, n);
        __builtin_amdgcn_s_setprio(1);
#pragma unroll
        for (int m = 0; m < 4; ++m)
#pragma unroll
            for (int n = 0; n < 8; ++n)
                acc[m][n] = __builtin_amdgcn_mfma_f32_16x16x32_f16(a[m], b[n], acc[m][n], 0, 0, 0);
        __builtin_amdgcn_s_setprio(0);
        if (t + 2 < NT) { // t+1 landed; t+2's 6 loads remain in flight
            asm volatile("s_waitcnt vmcnt(6)" ::: "memory");
        } else if (t + 1 < NT) { // penultimate: drain the final tile
            asm volatile("s_waitcnt vmcnt(0)" ::: "memory");
        }
        __builtin_amdgcn_s_barrier();
        if (++buf >= 3) buf = 0;
    }
    // ---- epilogue
    if (MODE == 1) {
#pragma unroll
        for (int n = 0; n < 8; ++n) {
            const int col = n0 + wc * 128 + n * 16 + lr;
            const float bvv = b0[col];
#pragma unroll
            for (int m = 0; m < 4; ++m) {
                const int row = m0 + wr * 64 + m * 16 + lg * 4;
#pragma unroll
                for (int r = 0; r < 4; ++r)
                    Cout[(size_t)(row + r) * D_ + col] = acc[m][n][r] + bvv;
            }
        }
    } else {
        const float* bias = (seg == 0) ? b0 : (seg == 1) ? b1 : b2;
#pragma unroll
        for (int n = 0; n < 8; ++n) {
            const int col = n0 + wc * 128 + n * 16 + lr;
            const int lc = col & 1023;
            const float bvv = bias[lc];
#pragma unroll
            for (int m = 0; m < 4; ++m) {
                const int row = m0 + wr * 64 + m * 16 + lg * 4;
                if (seg == 2) { // V transposed: VT[B][H*HD][S]
                    const int bb = row >> 11, s0 = row & 2047;
                    f16x4 v;
#pragma unroll
                    for (int r = 0; r < 4; ++r) v[r] = (f16)(acc[m][n][r] + bvv);
                    *reinterpret_cast<f16x4*>(VtB + ((size_t)(bb * D_ + lc)) * S_ + s0) = v;
                } else {
                    f16* dst = seg ? Kb : Qb;
#pragma unroll
                    for (int r = 0; r < 4; ++r)
                        dst[(size_t)(row + r) * D_ + lc] = (f16)(acc[m][n][r] + bvv);
                }
            }
        }
    }
}

// ---------------------------------------------------------------- causal flash attention
// grid (H, B, 8), 256 threads = 4 waves. Block handles q-tiles {15-pp, pp}.
// K,V staged to LDS via global_load_lds, double-buffered, XOR-swizzled both sides.
// Counted vmcnt(4). Swapped QK^T; scale fused into exp FMA; defer-max.
// lsum via ones-MFMA: row-sums accumulate in the zacc layout (no VALU sum, no shfls).
__global__ __launch_bounds__(256, 2) void attn_kernel(const f16* __restrict__ Q,
                                                      const f16* __restrict__ Kg,
                                                      const f16* __restrict__ Vt,
                                                      f16* __restrict__ Z) {
    __shared__ __align__(16) f16 KL[2][64 * 64];
    __shared__ __align__(16) f16 VL[2][64 * 64];
    __shared__ __align__(16) f16 Pl[4][32][72];
    const int h = blockIdx.x, b = blockIdx.y, pp = blockIdx.z;
    const int tid = threadIdx.x, w = tid >> 6, l = tid & 63, lr = l & 15, lg = l >> 4;
    const size_t base   = ((size_t)b * S_) * D_ + h * HD_;
    const size_t vtbase = ((size_t)(b * D_ + h * HD_)) * S_;
    const f16* __restrict__ Kbase = Kg + base;
    const f16* __restrict__ Vbase = Vt + vtbase;
    const float sc = 0.125f * 1.44269504f; // 1/sqrt(64) * log2(e)
    const int sw_xor = lr & 7;
    f16x8 onesv;
#pragma unroll
    for (int i = 0; i < 8; ++i) onesv[i] = (f16)1.0f;

    auto stageKV = [&](int buf, int t0) {
#pragma unroll
        for (int i = 0; i < 2; ++i) {
            const int c = i * 256 + tid;
            const int row = c >> 3, g16 = (c & 7) ^ (row & 7);
            f16* dstK = &KL[buf][(i * 256 + w * 64) * 8];
            f16* dstV = &VL[buf][(i * 256 + w * 64) * 8];
            gload_lds16(Kbase + (size_t)(t0 + row) * D_ + g16 * 8, dstK);
            gload_lds16(Vbase + (size_t)row * S_ + t0 + g16 * 8, dstV);
        }
    };

    for (int half = 0; half < 2; ++half) {
        const int qt = half ? pp : (15 - pp);
        const int q0 = qt * 128, wq0 = q0 + w * 32;
        const int ntw = ((wq0 + 31) >> 6) + 1;
        const int ntb = qt * 2 + 2;

        f16x8 qf[2][2];
#pragma unroll
        for (int mf = 0; mf < 2; ++mf)
#pragma unroll
            for (int kd = 0; kd < 2; ++kd)
                qf[mf][kd] = *reinterpret_cast<const f16x8*>(
                    Q + base + (size_t)(wq0 + mf * 16 + lr) * D_ + kd * 32 + lg * 8);

        f32x4 zacc[2][4] = {};
        f32x4 lsv[2] = {};                    // row-sums (zacc layout: row = lg*4+r)
        float mrun[2] = {-3.0e38f, -3.0e38f};

        stageKV(0, 0);
        for (int t = 0; t < ntb; ++t) {
            const int buf = t & 1;
            if (t + 1 < ntb) {
                stageKV(buf ^ 1, (t + 1) * 64);
                asm volatile("s_waitcnt vmcnt(4)" ::: "memory");
            } else {
                asm volatile("s_waitcnt vmcnt(0)" ::: "memory");
            }
            __builtin_amdgcn_s_barrier();
            if (t < ntw) {
                const int t0 = t * 64;
                f16x8 kf[2][4];
#pragma unroll
                for (int kd = 0; kd < 2; ++kd)
#pragma unroll
                    for (int n = 0; n < 4; ++n)
                        kf[kd][n] = *reinterpret_cast<const f16x8*>(
                            &KL[buf][(n * 16 + lr) * 64 + (((kd * 4 + lg) ^ sw_xor) * 8)]);
                f32x4 sf[2][4] = {};
                __builtin_amdgcn_s_setprio(1);
#pragma unroll
                for (int kd = 0; kd < 2; ++kd)
#pragma unroll
                    for (int n = 0; n < 4; ++n)
#pragma unroll
                        for (int mf = 0; mf < 2; ++mf)
                            sf[mf][n] = __builtin_amdgcn_mfma_f32_16x16x32_f16(kf[kd][n], qf[mf][kd], sf[mf][n], 0, 0, 0);
                __builtin_amdgcn_s_setprio(0);
                f16x8 vf[2][4];
#pragma unroll
                for (int kt = 0; kt < 2; ++kt)
#pragma unroll
                    for (int n = 0; n < 4; ++n)
                        vf[kt][n] = *reinterpret_cast<const f16x8*>(
                            &VL[buf][(n * 16 + lr) * 64 + (((kt * 4 + lg) ^ sw_xor) * 8)]);
                // mask only (raw scores); scale folds into the exp FMA below
                if (t == ntw - 1) {
#pragma unroll
                    for (int mf = 0; mf < 2; ++mf)
#pragma unroll
                        for (int n = 0; n < 4; ++n)
#pragma unroll
                            for (int r = 0; r < 4; ++r)
                                if ((t0 + n * 16 + lg * 4 + r) > (wq0 + mf * 16 + lr))
                                    sf[mf][n][r] = -3.0e38f;
                }
#pragma unroll
                for (int mf = 0; mf < 2; ++mf) {
                    f32x4 t4;
#pragma unroll
                    for (int r = 0; r < 4; ++r)
                        t4[r] = fmaxf(fmaxf(sf[mf][0][r], sf[mf][1][r]), fmaxf(sf[mf][2][r], sf[mf][3][r]));
                    float vmax = fmaxf(fmaxf(t4[0], t4[1]), fmaxf(t4[2], t4[3]));
                    vmax = fmaxf(vmax, __shfl_xor(vmax, 16));
                    vmax = fmaxf(vmax, __shfl_xor(vmax, 32));
                    const float vs = vmax * sc;
                    const bool norm = !__all(vs <= mrun[mf] + 10.0f);
                    if (norm) {
                        const float mnew = fmaxf(mrun[mf], vs);
                        const float al = __builtin_amdgcn_exp2f(mrun[mf] - mnew);
                        mrun[mf] = mnew;
#pragma unroll
                        for (int r = 0; r < 4; ++r) {
                            const float ar = __shfl(al, lg * 4 + r);
#pragma unroll
                            for (int n = 0; n < 4; ++n) zacc[mf][n][r] *= ar;
                            lsv[mf][r] *= ar;
                        }
                    }
#pragma unroll
                    for (int n = 0; n < 4; ++n) {
                        f32x4 p;
#pragma unroll
                        for (int r = 0; r < 4; ++r)
                            p[r] = __builtin_amdgcn_exp2f(fmaf(sf[mf][n][r], sc, -mrun[mf]));
                        f16x4 pv;
#pragma unroll
                        for (int r = 0; r < 4; ++r) pv[r] = (f16)p[r];
                        *reinterpret_cast<f16x4*>(&Pl[w][mf * 16 + lr][n * 16 + lg * 4]) = pv;
                    }
                }
#pragma unroll
                for (int kt = 0; kt < 2; ++kt) {
                    f16x8 pa[2];
#pragma unroll
                    for (int mf = 0; mf < 2; ++mf)
                        pa[mf] = *reinterpret_cast<const f16x8*>(&Pl[w][mf * 16 + lr][kt * 32 + lg * 8]);
                    __builtin_amdgcn_s_setprio(1);
#pragma unroll
                    for (int n = 0; n < 4; ++n)
#pragma unroll
                        for (int mf = 0; mf < 2; ++mf)
                            zacc[mf][n] = __builtin_amdgcn_mfma_f32_16x16x32_f16(pa[mf], vf[kt][n], zacc[mf][n], 0, 0, 0);
#pragma unroll
                    for (int mf = 0; mf < 2; ++mf)
                        lsv[mf] = __builtin_amdgcn_mfma_f32_16x16x32_f16(pa[mf], onesv, lsv[mf], 0, 0, 0);
                    __builtin_amdgcn_s_setprio(0);
                }
            }
            __builtin_amdgcn_s_barrier();
        }
#pragma unroll
        for (int mf = 0; mf < 2; ++mf) {
            f32x4 inv;
#pragma unroll
            for (int r = 0; r < 4; ++r) inv[r] = 1.0f / lsv[mf][r];
#pragma unroll
            for (int r = 0; r < 4; ++r)
#pragma unroll
                for (int n = 0; n < 4; ++n)
                    Z[base + (size_t)(wq0 + mf * 16 + lg * 4 + r) * D_ + n * 16 + lr] =
                        (f16)(zacc[mf][n][r] * inv[r]);
        }
    }
}

// ---------------------------------------------------------------- launcher
extern "C" void kernel_launch(void* const* d_in, const int* in_sizes, int n_in,
                              void* d_out, int out_size, void* d_ws, size_t ws_size,
                              hipStream_t stream) {
    const float* data    = (const float*)d_in[0];
    const float* context = (const float*)d_in[1];
    const float* Wq = (const float*)d_in[2];
    const float* bq = (const float*)d_in[3];
    const float* Wk = (const float*)d_in[4];
    const float* bk = (const float*)d_in[5];
    const float* Wv = (const float*)d_in[6];
    const float* bv = (const float*)d_in[7];
    const float* Wo = (const float*)d_in[8];
    const float* bo = (const float*)d_in[9];

    const size_t MD = (size_t)M_ * D_;
    const size_t DD = (size_t)D_ * D_;
    f16* dataB = (f16*)d_ws;
    f16* ctxB  = dataB + MD;
    f16* WqT   = ctxB + MD;   // WqT,WkT,WvT,WoT contiguous
    f16* WkT   = WqT + DD;
    f16* WvT   = WkT + DD;
    f16* WoT   = WvT + DD;
    f16* Qb    = WoT + DD;
    f16* Kb    = Qb + MD;
    f16* VtB   = Kb + MD;     // [B][H][HD][S]
    f16* Zb    = VtB + MD;

    (void)WkT; (void)WvT;

    const int n4 = (int)(MD / 4);
    cvt2_kernel<<<2 * n4 / 256, 256, 0, stream>>>(data, context, dataB, n4);
    transpose_cvt4_kernel<<<dim3(32, 32, 4), 256, 0, stream>>>(Wq, Wk, Wv, Wo, WqT);

    hipFuncSetAttribute(reinterpret_cast<const void*>(gemm3p<0>),
                        hipFuncAttributeMaxDynamicSharedMemorySize, 73728);
    hipFuncSetAttribute(reinterpret_cast<const void*>(gemm3p<1>),
                        hipFuncAttributeMaxDynamicSharedMemorySize, 73728);

    gemm3p<0><<<768, 256, 73728, stream>>>(dataB, ctxB, WqT, bq, bk, bv,
                                           Qb, Kb, VtB, nullptr);

    attn_kernel<<<dim3(H_, B_, 8), 256, 0, stream>>>(Qb, Kb, VtB, Zb);

    gemm3p<1><<<256, 256, 73728, stream>>>(Zb, nullptr, WoT, bo, nullptr, nullptr,
                                           nullptr, nullptr, nullptr, (float*)d_out);
}